// Round 2
// baseline (3223.243 us; speedup 1.0000x reference)
//
#include <hip/hip_runtime.h>
#include <cstdint>
#include <cstddef>

#define B_ 2
#define T_ 4096
#define D_ 2048
#define H_ 8
#define DK_ 128
#define DV_ 256
#define BT_ (B_*T_)
#define NQK_ 1024
#define NV_ 2048
#define N1_ 6144   // packed: q[0,1024) k[1024,2048) v[2048,4096) gate[4096,6144)

typedef __bf16 bf16x8 __attribute__((ext_vector_type(8)));
typedef float f32x4 __attribute__((ext_vector_type(4)));

#define GAS __attribute__((address_space(1)))
#define LAS __attribute__((address_space(3)))

__device__ __forceinline__ float bfu(unsigned short u) {
  union { unsigned int i; float f; } c; c.i = ((unsigned int)u) << 16; return c.f;
}
__device__ __forceinline__ float bflo(unsigned int u) {
  union { unsigned int i; float f; } c; c.i = u << 16; return c.f;
}
__device__ __forceinline__ float bfhi(unsigned int u) {
  union { unsigned int i; float f; } c; c.i = u & 0xFFFF0000u; return c.f;
}
__device__ __forceinline__ unsigned short f2bf(float f) {
  union { float f; unsigned int i; } c; c.f = f;
  unsigned int x = c.i;
  x += 0x7FFFu + ((x >> 16) & 1u);
  return (unsigned short)(x >> 16);
}
__device__ __forceinline__ unsigned int pack2(float a, float b) {
  return (unsigned int)f2bf(a) | ((unsigned int)f2bf(b) << 16);
}
__device__ __forceinline__ float siluf(float x) { return x / (1.f + __expf(-x)); }
__device__ __forceinline__ float redsum32(float v) {
  #pragma unroll
  for (int m = 16; m >= 1; m >>= 1) v += __shfl_xor(v, m);
  return v;
}
__device__ __forceinline__ void async_copy16(void* lds, const void* gsrc) {
  __builtin_amdgcn_global_load_lds((const GAS unsigned int*)gsrc,
                                   (LAS unsigned int*)lds, 16, 0, 0);
}

// ---------------- cast x (f32 -> bf16) ----------------
__global__ __launch_bounds__(256) void cast_x_kernel(const float* __restrict__ in,
                                                     unsigned short* __restrict__ out) {
  size_t i = ((size_t)blockIdx.x * 256 + threadIdx.x) * 4;
  float4 v = *(const float4*)(in + i);
  uint2 r;
  r.x = pack2(v.x, v.y);
  r.y = pack2(v.z, v.w);
  *(uint2*)(out + i) = r;
}

// ---------------- transpose + cast weight (f32 [R][C] -> bf16 [C][R]) ----------------
__global__ __launch_bounds__(256) void transpose_cast(const float* __restrict__ in,
                                                      unsigned short* __restrict__ out,
                                                      int R, int Cc) {
  __shared__ float tile[32][33];
  int c0 = blockIdx.x * 32, r0 = blockIdx.y * 32;
  int tx = threadIdx.x, ty = threadIdx.y;  // (32,8)
  #pragma unroll
  for (int i = 0; i < 4; ++i)
    tile[ty + i*8][tx] = in[(size_t)(r0 + ty + i*8) * Cc + c0 + tx];
  __syncthreads();
  #pragma unroll
  for (int i = 0; i < 4; ++i)
    out[(size_t)(c0 + ty + i*8) * R + r0 + tx] = f2bf(tile[tx][ty + i*8]);
}

// ---------------- bf16 MFMA GEMM: C[M,N] = A[M,K] * Bt[N,K]^T ----------------
// 128x128 tile, 4 waves (2x2), 16x16x32 bf16 MFMA, global_load_lds staging.
template<int BF16OUT>
__global__ __launch_bounds__(256) void gemm_kernel(
    const unsigned short* __restrict__ A,   // [M][K] bf16
    const unsigned short* __restrict__ Bt,  // [N][K] bf16
    void* __restrict__ Cout,
    int M, int N, int K)
{
  __shared__ __align__(16) unsigned short As[128][32];
  __shared__ __align__(16) unsigned short Bs[128][32];
  const int tid  = threadIdx.x;
  const int lane = tid & 63;
  const int wave = tid >> 6;
  const int wr = wave >> 1, wc = wave & 1;
  const int row0 = blockIdx.y * 128, col0 = blockIdx.x * 128;
  f32x4 acc[4][4];
  #pragma unroll
  for (int m = 0; m < 4; ++m)
    #pragma unroll
    for (int n = 0; n < 4; ++n)
      acc[m][n] = (f32x4){0.f, 0.f, 0.f, 0.f};

  const int fr = lane & 15;   // row within 16x16 frag
  const int fq = lane >> 4;   // k-quad (8 contiguous k per lane)

  for (int k0 = 0; k0 < K; k0 += 32) {
    #pragma unroll
    for (int i = 0; i < 2; ++i) {
      int c = tid + i * 256;          // chunk id 0..511 -> LDS byte c*16 (linear)
      int r = c >> 2, o = (c & 3) * 8;
      async_copy16(&As[r][o], A  + (size_t)(row0 + r) * K + k0 + o);
      async_copy16(&Bs[r][o], Bt + (size_t)(col0 + r) * K + k0 + o);
    }
    asm volatile("s_waitcnt vmcnt(0)" ::: "memory");
    __syncthreads();
    bf16x8 af[4], bfr[4];
    #pragma unroll
    for (int m = 0; m < 4; ++m)
      af[m] = *(const bf16x8*)&As[wr*64 + m*16 + fr][fq*8];
    #pragma unroll
    for (int n = 0; n < 4; ++n)
      bfr[n] = *(const bf16x8*)&Bs[wc*64 + n*16 + fr][fq*8];
    #pragma unroll
    for (int m = 0; m < 4; ++m)
      #pragma unroll
      for (int n = 0; n < 4; ++n)
        acc[m][n] = __builtin_amdgcn_mfma_f32_16x16x32_bf16(af[m], bfr[n], acc[m][n], 0, 0, 0);
    __syncthreads();
  }
  // C/D layout: col = lane&15, row = (lane>>4)*4 + reg
  const int fc = lane & 15, fg = lane >> 4;
  #pragma unroll
  for (int m = 0; m < 4; ++m)
    #pragma unroll
    for (int n = 0; n < 4; ++n)
      #pragma unroll
      for (int r = 0; r < 4; ++r) {
        size_t idx = (size_t)(row0 + wr*64 + m*16 + fg*4 + r) * N
                   + (col0 + wc*64 + n*16 + fc);
        if (BF16OUT) ((unsigned short*)Cout)[idx] = f2bf(acc[m][n][r]);
        else         ((float*)Cout)[idx]          = acc[m][n][r];
      }
}

// ---------------- beta / g projection (f32, N=16) ----------------
__global__ __launch_bounds__(256) void beta_g_kernel(
    const float* __restrict__ x, const float* __restrict__ Wb, const float* __restrict__ Wa,
    const float* __restrict__ A_log, const float* __restrict__ dtb,
    float* __restrict__ beta, float* __restrict__ g)
{
  const int t = blockIdx.x;
  const int wave = threadIdx.x >> 6;
  const int lane = threadIdx.x & 63;
  const float* xr = x + (size_t)t * D_;
  float acc[4] = {0.f, 0.f, 0.f, 0.f};
  for (int k = lane; k < D_; k += 64) {
    float xv = xr[k];
    #pragma unroll
    for (int i = 0; i < 4; ++i) {
      int o = wave + 4 * i;                 // 0..7: beta heads, 8..15: a heads
      float w = (o < 8) ? Wb[(size_t)k * 8 + o] : Wa[(size_t)k * 8 + (o - 8)];
      acc[i] += xv * w;
    }
  }
  #pragma unroll
  for (int i = 0; i < 4; ++i) {
    #pragma unroll
    for (int m = 32; m >= 1; m >>= 1) acc[i] += __shfl_xor(acc[i], m);
  }
  if (lane == 0) {
    #pragma unroll
    for (int i = 0; i < 4; ++i) {
      int o = wave + 4 * i;
      if (o < 8) {
        beta[(size_t)t * H_ + o] = 1.f / (1.f + __expf(-acc[i]));
      } else {
        int h = o - 8;
        float z = acc[i] + dtb[h];
        float sp = (z > 20.f) ? z : log1pf(__expf(z));
        g[(size_t)t * H_ + h] = -__expf(A_log[h]) * sp;
      }
    }
  }
}

// ---------------- causal dwconv(W=4) + silu + l2norm ----------------
__global__ __launch_bounds__(256) void conv_kernel(
    const unsigned short* __restrict__ Y1,
    const float* __restrict__ cq, const float* __restrict__ ck, const float* __restrict__ cv,
    float* __restrict__ qf, float* __restrict__ kf, float* __restrict__ vf)
{
  const int t  = blockIdx.x;          // global row (b*T + tt)
  const int tt = t & (T_ - 1);
  const int tid = threadIdx.x;
  const int c4 = tid * 4;
  const int c8 = tid * 8;

  float wqa[4][4], wka[4][4], wva[8][4];
  #pragma unroll
  for (int m = 0; m < 4; ++m) {
    float4 a = *(const float4*)(cq + (size_t)(c4 + m) * 4);
    wqa[m][0] = a.x; wqa[m][1] = a.y; wqa[m][2] = a.z; wqa[m][3] = a.w;
    float4 b = *(const float4*)(ck + (size_t)(c4 + m) * 4);
    wka[m][0] = b.x; wka[m][1] = b.y; wka[m][2] = b.z; wka[m][3] = b.w;
  }
  #pragma unroll
  for (int m = 0; m < 8; ++m) {
    float4 a = *(const float4*)(cv + (size_t)(c8 + m) * 4);
    wva[m][0] = a.x; wva[m][1] = a.y; wva[m][2] = a.z; wva[m][3] = a.w;
  }

  float aq[4] = {0,0,0,0}, ak[4] = {0,0,0,0}, av[8] = {0,0,0,0,0,0,0,0};
  #pragma unroll
  for (int i = 0; i < 4; ++i) {
    if (tt + i >= 3) {      // tap i reads x[t-3+i]
      const unsigned short* row = Y1 + (size_t)(t + i - 3) * N1_;
      ushort4 yq = *(const ushort4*)(row + c4);
      ushort4 yk = *(const ushort4*)(row + NQK_ + c4);
      int4    yv = *(const int4*)(row + 2 * NQK_ + c8);
      float qv[4] = { bfu(yq.x), bfu(yq.y), bfu(yq.z), bfu(yq.w) };
      float kv[4] = { bfu(yk.x), bfu(yk.y), bfu(yk.z), bfu(yk.w) };
      unsigned int vu[4] = { (unsigned)yv.x, (unsigned)yv.y, (unsigned)yv.z, (unsigned)yv.w };
      float vv[8] = { bflo(vu[0]), bfhi(vu[0]), bflo(vu[1]), bfhi(vu[1]),
                      bflo(vu[2]), bfhi(vu[2]), bflo(vu[3]), bfhi(vu[3]) };
      #pragma unroll
      for (int m = 0; m < 4; ++m) { aq[m] += qv[m] * wqa[m][i]; ak[m] += kv[m] * wka[m][i]; }
      #pragma unroll
      for (int m = 0; m < 8; ++m) av[m] += vv[m] * wva[m][i];
    }
  }
  float sq[4], sk[4], ssq = 0.f, ssk = 0.f;
  #pragma unroll
  for (int m = 0; m < 4; ++m) {
    sq[m] = siluf(aq[m]); ssq += sq[m] * sq[m];
    sk[m] = siluf(ak[m]); ssk += sk[m] * sk[m];
  }
  ssq = redsum32(ssq);   // head = tid/32; 32-lane groups align with heads
  ssk = redsum32(ssk);
  float scq = rsqrtf(ssq + 1e-6f) * 0.08838834764831845f;  // * DK^-0.5
  float sck = rsqrtf(ssk + 1e-6f);
  float4 oq = { sq[0]*scq, sq[1]*scq, sq[2]*scq, sq[3]*scq };
  float4 ok = { sk[0]*sck, sk[1]*sck, sk[2]*sck, sk[3]*sck };
  *(float4*)(qf + (size_t)t * NQK_ + c4) = oq;
  *(float4*)(kf + (size_t)t * NQK_ + c4) = ok;
  float4 ov0 = { siluf(av[0]), siluf(av[1]), siluf(av[2]), siluf(av[3]) };
  float4 ov1 = { siluf(av[4]), siluf(av[5]), siluf(av[6]), siluf(av[7]) };
  *(float4*)(vf + (size_t)t * NV_ + c8)     = ov0;
  *(float4*)(vf + (size_t)t * NV_ + c8 + 4) = ov1;
}

// ---------------- gated delta-rule recurrence ----------------
// One wave per (b,h, column-pair). 32 lanes per DV-column, 4 state elems/lane.
// NOTE: o may alias vf — each lane reads vf[t+1] before writing o[t] at the
// same column; columns are disjoint across waves, rows only move forward.
__global__ __launch_bounds__(64) void delta_kernel(
    const float* __restrict__ qf, const float* __restrict__ kf,
    const float* __restrict__ vf,
    const float* __restrict__ g, const float* __restrict__ beta,
    float* __restrict__ o)
{
  const int blk = blockIdx.x;
  const int bh = blk & 15;     // fastest-varying -> same bh clusters per XCD (bid%8)
  const int jp = blk >> 4;     // 0..127 column pair
  const int b = bh >> 3, h = bh & 7;
  const int lane = threadIdx.x;
  const int r = lane & 31;
  const int j = jp * 2 + (lane >> 5);

  const float* qp = qf + (size_t)(b * T_) * (H_ * DK_) + h * DK_ + r * 4;
  const float* kp = kf + (size_t)(b * T_) * (H_ * DK_) + h * DK_ + r * 4;
  const float* vp = vf + (size_t)(b * T_) * (H_ * DV_) + h * DV_ + j;
  const float* gp = g    + (size_t)(b * T_) * H_ + h;
  const float* bp = beta + (size_t)(b * T_) * H_ + h;
  float*       op = o  + (size_t)(b * T_) * (H_ * DV_) + h * DV_ + j;

  float S0 = 0.f, S1 = 0.f, S2 = 0.f, S3 = 0.f;
  float4 kd = *(const float4*)kp;
  float4 qd = *(const float4*)qp;
  float vv = *vp;
  float gg = *gp, bt = *bp;
  for (int t = 0; t < T_; ++t) {
    kp += H_ * DK_; qp += H_ * DK_; vp += H_ * DV_; gp += H_; bp += H_;
    float4 kd2 = *(const float4*)kp;    // prefetch next step (one-row over-read
    float4 qd2 = *(const float4*)qp;    //  at t=T_-1 stays inside ws by layout)
    float vv2 = *vp;
    float gg2 = *gp, bt2 = *bp;

    float gamma = __expf(gg);
    float dot0 = kd.x*S0 + kd.y*S1 + kd.z*S2 + kd.w*S3;
    dot0 += __shfl_xor(dot0, 1);
    dot0 += __shfl_xor(dot0, 2);
    dot0 += __shfl_xor(dot0, 4);
    dot0 += __shfl_xor(dot0, 8);
    dot0 += __shfl_xor(dot0, 16);
    float u = bt * (vv - gamma * dot0);
    S0 = gamma * S0 + kd.x * u;
    S1 = gamma * S1 + kd.y * u;
    S2 = gamma * S2 + kd.z * u;
    S3 = gamma * S3 + kd.w * u;
    float od = qd.x*S0 + qd.y*S1 + qd.z*S2 + qd.w*S3;
    od += __shfl_xor(od, 1);
    od += __shfl_xor(od, 2);
    od += __shfl_xor(od, 4);
    od += __shfl_xor(od, 8);
    od += __shfl_xor(od, 16);
    if (r == 0) *op = od;
    op += H_ * DV_;
    kd = kd2; qd = qd2; vv = vv2; gg = gg2; bt = bt2;
  }
}

// ---------------- gated RMSNorm + silu(gate) -> bf16 ----------------
__global__ __launch_bounds__(256) void post_kernel(
    const float* __restrict__ o, const unsigned short* __restrict__ Y1,
    const float* __restrict__ gw, unsigned short* __restrict__ og)
{
  const int t = blockIdx.x;
  const int tid = threadIdx.x;
  const int e = tid * 8;       // head = tid/32, dv = e&255
  float4 v0 = *(const float4*)(o + (size_t)t * NV_ + e);
  float4 v1 = *(const float4*)(o + (size_t)t * NV_ + e + 4);
  float v[8] = { v0.x, v0.y, v0.z, v0.w, v1.x, v1.y, v1.z, v1.w };
  float ss = 0.f;
  #pragma unroll
  for (int m = 0; m < 8; ++m) ss += v[m] * v[m];
  ss = redsum32(ss);
  float rms = rsqrtf(ss * (1.f / 256.f) + 1e-5f);
  int4 graw = *(const int4*)(Y1 + (size_t)t * N1_ + 4096 + e);
  unsigned int gu[4] = { (unsigned)graw.x, (unsigned)graw.y, (unsigned)graw.z, (unsigned)graw.w };
  float gv[8] = { bflo(gu[0]), bfhi(gu[0]), bflo(gu[1]), bfhi(gu[1]),
                  bflo(gu[2]), bfhi(gu[2]), bflo(gu[3]), bfhi(gu[3]) };
  const int dv = e & 255;
  float res[8];
  #pragma unroll
  for (int m = 0; m < 8; ++m) res[m] = v[m] * rms * gw[dv + m] * siluf(gv[m]);
  int4 outv;
  outv.x = (int)pack2(res[0], res[1]);
  outv.y = (int)pack2(res[2], res[3]);
  outv.z = (int)pack2(res[4], res[5]);
  outv.w = (int)pack2(res[6], res[7]);
  *(int4*)(og + (size_t)t * NV_ + e) = outv;
}

extern "C" void kernel_launch(void* const* d_in, const int* in_sizes, int n_in,
                              void* d_out, int out_size, void* d_ws, size_t ws_size,
                              hipStream_t stream)
{
  (void)in_sizes; (void)n_in; (void)out_size;
  const float* x     = (const float*)d_in[0];
  const float* Wq    = (const float*)d_in[1];
  const float* Wk    = (const float*)d_in[2];
  const float* Wv    = (const float*)d_in[3];
  const float* Wb    = (const float*)d_in[4];
  const float* Wa    = (const float*)d_in[5];
  const float* Wg    = (const float*)d_in[6];
  const float* Wo    = (const float*)d_in[7];
  const float* cq    = (const float*)d_in[8];
  const float* ck    = (const float*)d_in[9];
  const float* cv    = (const float*)d_in[10];
  const float* A_log = (const float*)d_in[11];
  const float* dtb   = (const float*)d_in[12];
  const float* gw    = (const float*)d_in[13];

  // ---- workspace layout with lifetime-based aliasing (peak ~232.5 MiB) ----
  // Region R1 [0, 128MiB):
  //   phase A (cast/transpose/gemm1): xb [0,32MiB) + Wct [32,56MiB)
  //   phase B (conv/delta):           qf [0,32MiB) + kf [32,64MiB) + vf/ov [64,128MiB)
  //   phase C (post/gemm2):           og [0,32MiB)  (qf dead)
  // Then: Wot (8MiB), beta, gl, Y1. Ordering guarantees delta's one-row
  // prefetch over-read of qf/kf/vf/beta/gl lands in the next live buffer.
  char* ws = (char*)d_ws;
  const size_t SZ_XB  = (size_t)BT_ * D_ * 2;       // 32 MiB
  const size_t SZ_WCT = (size_t)N1_ * D_ * 2;       // 24 MiB
  const size_t SZ_QF  = (size_t)BT_ * NQK_ * 4;     // 32 MiB
  const size_t SZ_KF  = (size_t)BT_ * NQK_ * 4;     // 32 MiB
  const size_t SZ_VF  = (size_t)BT_ * NV_ * 4;      // 64 MiB
  const size_t SZ_R1a = SZ_XB + SZ_WCT;
  const size_t SZ_R1b = SZ_QF + SZ_KF + SZ_VF;
  const size_t SZ_R1  = (SZ_R1a > SZ_R1b) ? SZ_R1a : SZ_R1b;
  const size_t SZ_WOT = (size_t)D_ * D_ * 2;        // 8 MiB
  const size_t SZ_BG  = (size_t)BT_ * H_ * 4;       // 256 KiB each
  const size_t SZ_Y1  = (size_t)BT_ * N1_ * 2;      // 96 MiB

  const size_t OFF_WOT  = SZ_R1;
  const size_t OFF_BETA = OFF_WOT + SZ_WOT;
  const size_t OFF_GL   = OFF_BETA + SZ_BG;
  const size_t OFF_Y1   = OFF_GL + SZ_BG;
  const size_t WS_NEEDED = OFF_Y1 + SZ_Y1;
  if (ws_size < WS_NEEDED) return;   // diagnostic: absmax == ref-max ==> ws too small

  unsigned short* xb  = (unsigned short*)(ws);                 // phase A
  unsigned short* Wct = (unsigned short*)(ws + SZ_XB);         // phase A
  float* qf = (float*)(ws);                                    // phase B
  float* kf = (float*)(ws + SZ_QF);                            // phase B
  float* vf = (float*)(ws + SZ_QF + SZ_KF);                    // phase B/C (ov aliases)
  float* ov = vf;
  unsigned short* og  = (unsigned short*)(ws);                 // phase C
  unsigned short* Wot = (unsigned short*)(ws + OFF_WOT);
  float* beta = (float*)(ws + OFF_BETA);
  float* gl   = (float*)(ws + OFF_GL);
  unsigned short* Y1  = (unsigned short*)(ws + OFF_Y1);

  cast_x_kernel<<<(BT_ * D_) / 1024, 256, 0, stream>>>(x, xb);
  dim3 tb(32, 8);
  transpose_cast<<<dim3(1024/32, 2048/32), tb, 0, stream>>>(Wq, Wct, 2048, 1024);
  transpose_cast<<<dim3(1024/32, 2048/32), tb, 0, stream>>>(Wk, Wct + (size_t)1024 * 2048, 2048, 1024);
  transpose_cast<<<dim3(2048/32, 2048/32), tb, 0, stream>>>(Wv, Wct + (size_t)2048 * 2048, 2048, 2048);
  transpose_cast<<<dim3(2048/32, 2048/32), tb, 0, stream>>>(Wg, Wct + (size_t)4096 * 2048, 2048, 2048);
  transpose_cast<<<dim3(2048/32, 2048/32), tb, 0, stream>>>(Wo, Wot, 2048, 2048);

  gemm_kernel<1><<<dim3(N1_/128, BT_/128), 256, 0, stream>>>(xb, Wct, Y1, BT_, N1_, D_);
  beta_g_kernel<<<BT_, 256, 0, stream>>>(x, Wb, Wa, A_log, dtb, beta, gl);
  conv_kernel<<<BT_, 256, 0, stream>>>(Y1, cq, ck, cv, qf, kf, vf);
  delta_kernel<<<B_ * H_ * (DV_/2), 64, 0, stream>>>(qf, kf, vf, gl, beta, ov);
  post_kernel<<<BT_, 256, 0, stream>>>(ov, Y1, gw, og);
  gemm_kernel<0><<<dim3(D_/128, BT_/128), 256, 0, stream>>>(og, Wot, d_out, BT_, D_, D_);
}

// Round 3
// 3052.083 us; speedup vs baseline: 1.0561x; 1.0561x over previous
//
#include <hip/hip_runtime.h>
#include <cstdint>
#include <cstddef>

#define B_ 2
#define T_ 4096
#define D_ 2048
#define H_ 8
#define DK_ 128
#define DV_ 256
#define BT_ (B_*T_)
#define NQK_ 1024
#define NV_ 2048
#define N1_ 6144   // packed: q[0,1024) k[1024,2048) v[2048,4096) gate[4096,6144)

typedef __bf16 bf16x8 __attribute__((ext_vector_type(8)));
typedef float f32x4 __attribute__((ext_vector_type(4)));

#define GAS __attribute__((address_space(1)))
#define LAS __attribute__((address_space(3)))

__device__ __forceinline__ float bfu(unsigned short u) {
  union { unsigned int i; float f; } c; c.i = ((unsigned int)u) << 16; return c.f;
}
__device__ __forceinline__ float bflo(unsigned int u) {
  union { unsigned int i; float f; } c; c.i = u << 16; return c.f;
}
__device__ __forceinline__ float bfhi(unsigned int u) {
  union { unsigned int i; float f; } c; c.i = u & 0xFFFF0000u; return c.f;
}
__device__ __forceinline__ unsigned short f2bf(float f) {
  union { float f; unsigned int i; } c; c.f = f;
  unsigned int x = c.i;
  x += 0x7FFFu + ((x >> 16) & 1u);
  return (unsigned short)(x >> 16);
}
__device__ __forceinline__ unsigned int pack2(float a, float b) {
  return (unsigned int)f2bf(a) | ((unsigned int)f2bf(b) << 16);
}
__device__ __forceinline__ float siluf(float x) { return x / (1.f + __expf(-x)); }
__device__ __forceinline__ float redsum32(float v) {
  #pragma unroll
  for (int m = 16; m >= 1; m >>= 1) v += __shfl_xor(v, m);
  return v;
}
__device__ __forceinline__ void async_copy16(void* lds, const void* gsrc) {
  __builtin_amdgcn_global_load_lds((const GAS unsigned int*)gsrc,
                                   (LAS unsigned int*)lds, 16, 0, 0);
}

// ---- DPP wave reduction helpers (VALU-pipe cross-lane, ~10x lower latency
// ---- than ds-based __shfl_xor on the dependent chain) ----
template<int CTRL>
__device__ __forceinline__ float dpp_add(float x) {
  union { int i; float f; } a, r;
  a.f = x;
  r.i = __builtin_amdgcn_update_dpp(0, a.i, CTRL, 0xF, 0xF, true);
  return x + r.f;
}
// after this: lane31 = sum(lanes 0..31), lane63 = sum(lanes 32..63)
__device__ __forceinline__ float red32_dpp(float x) {
  x = dpp_add<0x111>(x);   // row_shr:1
  x = dpp_add<0x112>(x);   // row_shr:2
  x = dpp_add<0x114>(x);   // row_shr:4
  x = dpp_add<0x118>(x);   // row_shr:8
  x = dpp_add<0x142>(x);   // row_bcast:15
  return x;
}
__device__ __forceinline__ float bcast_halves(float x, int lane) {
  union { int i; float f; } a, lo, hi;
  a.f = x;
  lo.i = __builtin_amdgcn_readlane(a.i, 31);
  hi.i = __builtin_amdgcn_readlane(a.i, 63);
  return (lane & 32) ? hi.f : lo.f;
}

// ---------------- cast x (f32 -> bf16) ----------------
__global__ __launch_bounds__(256) void cast_x_kernel(const float* __restrict__ in,
                                                     unsigned short* __restrict__ out) {
  size_t i = ((size_t)blockIdx.x * 256 + threadIdx.x) * 4;
  float4 v = *(const float4*)(in + i);
  uint2 r;
  r.x = pack2(v.x, v.y);
  r.y = pack2(v.z, v.w);
  *(uint2*)(out + i) = r;
}

// ---------------- transpose + cast weight (f32 [R][C] -> bf16 [C][R]) ----------------
__global__ __launch_bounds__(256) void transpose_cast(const float* __restrict__ in,
                                                      unsigned short* __restrict__ out,
                                                      int R, int Cc) {
  __shared__ float tile[32][33];
  int c0 = blockIdx.x * 32, r0 = blockIdx.y * 32;
  int tx = threadIdx.x, ty = threadIdx.y;  // (32,8)
  #pragma unroll
  for (int i = 0; i < 4; ++i)
    tile[ty + i*8][tx] = in[(size_t)(r0 + ty + i*8) * Cc + c0 + tx];
  __syncthreads();
  #pragma unroll
  for (int i = 0; i < 4; ++i)
    out[(size_t)(c0 + ty + i*8) * R + r0 + tx] = f2bf(tile[tx][ty + i*8]);
}

// ---------------- bf16 MFMA GEMM: C[M,N] = A[M,K] * Bt[N,K]^T ----------------
// 128x128 tile, 4 waves (2x2), 16x16x32 bf16 MFMA, global_load_lds staging.
template<int BF16OUT>
__global__ __launch_bounds__(256) void gemm_kernel(
    const unsigned short* __restrict__ A,   // [M][K] bf16
    const unsigned short* __restrict__ Bt,  // [N][K] bf16
    void* __restrict__ Cout,
    int M, int N, int K)
{
  __shared__ __align__(16) unsigned short As[128][32];
  __shared__ __align__(16) unsigned short Bs[128][32];
  const int tid  = threadIdx.x;
  const int lane = tid & 63;
  const int wave = tid >> 6;
  const int wr = wave >> 1, wc = wave & 1;
  const int row0 = blockIdx.y * 128, col0 = blockIdx.x * 128;
  f32x4 acc[4][4];
  #pragma unroll
  for (int m = 0; m < 4; ++m)
    #pragma unroll
    for (int n = 0; n < 4; ++n)
      acc[m][n] = (f32x4){0.f, 0.f, 0.f, 0.f};

  const int fr = lane & 15;   // row within 16x16 frag
  const int fq = lane >> 4;   // k-quad (8 contiguous k per lane)

  for (int k0 = 0; k0 < K; k0 += 32) {
    #pragma unroll
    for (int i = 0; i < 2; ++i) {
      int c = tid + i * 256;          // chunk id 0..511 -> LDS byte c*16 (linear)
      int r = c >> 2, o = (c & 3) * 8;
      async_copy16(&As[r][o], A  + (size_t)(row0 + r) * K + k0 + o);
      async_copy16(&Bs[r][o], Bt + (size_t)(col0 + r) * K + k0 + o);
    }
    asm volatile("s_waitcnt vmcnt(0)" ::: "memory");
    __syncthreads();
    bf16x8 af[4], bfr[4];
    #pragma unroll
    for (int m = 0; m < 4; ++m)
      af[m] = *(const bf16x8*)&As[wr*64 + m*16 + fr][fq*8];
    #pragma unroll
    for (int n = 0; n < 4; ++n)
      bfr[n] = *(const bf16x8*)&Bs[wc*64 + n*16 + fr][fq*8];
    #pragma unroll
    for (int m = 0; m < 4; ++m)
      #pragma unroll
      for (int n = 0; n < 4; ++n)
        acc[m][n] = __builtin_amdgcn_mfma_f32_16x16x32_bf16(af[m], bfr[n], acc[m][n], 0, 0, 0);
    __syncthreads();
  }
  // C/D layout: col = lane&15, row = (lane>>4)*4 + reg
  const int fc = lane & 15, fg = lane >> 4;
  #pragma unroll
  for (int m = 0; m < 4; ++m)
    #pragma unroll
    for (int n = 0; n < 4; ++n)
      #pragma unroll
      for (int r = 0; r < 4; ++r) {
        size_t idx = (size_t)(row0 + wr*64 + m*16 + fg*4 + r) * N
                   + (col0 + wc*64 + n*16 + fc);
        if (BF16OUT) ((unsigned short*)Cout)[idx] = f2bf(acc[m][n][r]);
        else         ((float*)Cout)[idx]          = acc[m][n][r];
      }
}

// ---------------- beta / g projection (f32, N=16) ----------------
__global__ __launch_bounds__(256) void beta_g_kernel(
    const float* __restrict__ x, const float* __restrict__ Wb, const float* __restrict__ Wa,
    const float* __restrict__ A_log, const float* __restrict__ dtb,
    float* __restrict__ beta, float* __restrict__ g)
{
  const int t = blockIdx.x;
  const int wave = threadIdx.x >> 6;
  const int lane = threadIdx.x & 63;
  const float* xr = x + (size_t)t * D_;
  float acc[4] = {0.f, 0.f, 0.f, 0.f};
  for (int k = lane; k < D_; k += 64) {
    float xv = xr[k];
    #pragma unroll
    for (int i = 0; i < 4; ++i) {
      int o = wave + 4 * i;                 // 0..7: beta heads, 8..15: a heads
      float w = (o < 8) ? Wb[(size_t)k * 8 + o] : Wa[(size_t)k * 8 + (o - 8)];
      acc[i] += xv * w;
    }
  }
  #pragma unroll
  for (int i = 0; i < 4; ++i) {
    #pragma unroll
    for (int m = 32; m >= 1; m >>= 1) acc[i] += __shfl_xor(acc[i], m);
  }
  if (lane == 0) {
    #pragma unroll
    for (int i = 0; i < 4; ++i) {
      int o = wave + 4 * i;
      if (o < 8) {
        beta[(size_t)t * H_ + o] = 1.f / (1.f + __expf(-acc[i]));
      } else {
        int h = o - 8;
        float z = acc[i] + dtb[h];
        float sp = (z > 20.f) ? z : log1pf(__expf(z));
        g[(size_t)t * H_ + h] = -__expf(A_log[h]) * sp;
      }
    }
  }
}

// ---------------- causal dwconv(W=4) + silu + l2norm ----------------
__global__ __launch_bounds__(256) void conv_kernel(
    const unsigned short* __restrict__ Y1,
    const float* __restrict__ cq, const float* __restrict__ ck, const float* __restrict__ cv,
    float* __restrict__ qf, float* __restrict__ kf, float* __restrict__ vf)
{
  const int t  = blockIdx.x;          // global row (b*T + tt)
  const int tt = t & (T_ - 1);
  const int tid = threadIdx.x;
  const int c4 = tid * 4;
  const int c8 = tid * 8;

  float wqa[4][4], wka[4][4], wva[8][4];
  #pragma unroll
  for (int m = 0; m < 4; ++m) {
    float4 a = *(const float4*)(cq + (size_t)(c4 + m) * 4);
    wqa[m][0] = a.x; wqa[m][1] = a.y; wqa[m][2] = a.z; wqa[m][3] = a.w;
    float4 b = *(const float4*)(ck + (size_t)(c4 + m) * 4);
    wka[m][0] = b.x; wka[m][1] = b.y; wka[m][2] = b.z; wka[m][3] = b.w;
  }
  #pragma unroll
  for (int m = 0; m < 8; ++m) {
    float4 a = *(const float4*)(cv + (size_t)(c8 + m) * 4);
    wva[m][0] = a.x; wva[m][1] = a.y; wva[m][2] = a.z; wva[m][3] = a.w;
  }

  float aq[4] = {0,0,0,0}, ak[4] = {0,0,0,0}, av[8] = {0,0,0,0,0,0,0,0};
  #pragma unroll
  for (int i = 0; i < 4; ++i) {
    if (tt + i >= 3) {      // tap i reads x[t-3+i]
      const unsigned short* row = Y1 + (size_t)(t + i - 3) * N1_;
      ushort4 yq = *(const ushort4*)(row + c4);
      ushort4 yk = *(const ushort4*)(row + NQK_ + c4);
      int4    yv = *(const int4*)(row + 2 * NQK_ + c8);
      float qv[4] = { bfu(yq.x), bfu(yq.y), bfu(yq.z), bfu(yq.w) };
      float kv[4] = { bfu(yk.x), bfu(yk.y), bfu(yk.z), bfu(yk.w) };
      unsigned int vu[4] = { (unsigned)yv.x, (unsigned)yv.y, (unsigned)yv.z, (unsigned)yv.w };
      float vv[8] = { bflo(vu[0]), bfhi(vu[0]), bflo(vu[1]), bfhi(vu[1]),
                      bflo(vu[2]), bfhi(vu[2]), bflo(vu[3]), bfhi(vu[3]) };
      #pragma unroll
      for (int m = 0; m < 4; ++m) { aq[m] += qv[m] * wqa[m][i]; ak[m] += kv[m] * wka[m][i]; }
      #pragma unroll
      for (int m = 0; m < 8; ++m) av[m] += vv[m] * wva[m][i];
    }
  }
  float sq[4], sk[4], ssq = 0.f, ssk = 0.f;
  #pragma unroll
  for (int m = 0; m < 4; ++m) {
    sq[m] = siluf(aq[m]); ssq += sq[m] * sq[m];
    sk[m] = siluf(ak[m]); ssk += sk[m] * sk[m];
  }
  ssq = redsum32(ssq);   // head = tid/32; 32-lane groups align with heads
  ssk = redsum32(ssk);
  float scq = rsqrtf(ssq + 1e-6f) * 0.08838834764831845f;  // * DK^-0.5
  float sck = rsqrtf(ssk + 1e-6f);
  float4 oq = { sq[0]*scq, sq[1]*scq, sq[2]*scq, sq[3]*scq };
  float4 ok = { sk[0]*sck, sk[1]*sck, sk[2]*sck, sk[3]*sck };
  *(float4*)(qf + (size_t)t * NQK_ + c4) = oq;
  *(float4*)(kf + (size_t)t * NQK_ + c4) = ok;
  float4 ov0 = { siluf(av[0]), siluf(av[1]), siluf(av[2]), siluf(av[3]) };
  float4 ov1 = { siluf(av[4]), siluf(av[5]), siluf(av[6]), siluf(av[7]) };
  *(float4*)(vf + (size_t)t * NV_ + c8)     = ov0;
  *(float4*)(vf + (size_t)t * NV_ + c8 + 4) = ov1;
}

// ---------------- gated delta-rule recurrence ----------------
// One wave per (b,h, column-pair). 32 lanes per DV-column, 4 state elems/lane.
// Reductions via DPP (VALU pipe) instead of shfl (LDS pipe): the two 5-level
// shfl trees were ~1200 cyc of the measured 1342 cyc/step.
// NOTE: o may alias vf — each lane reads vf[t+1] before writing o[t] at the
// same column; columns are disjoint across waves, rows only move forward.
__global__ __launch_bounds__(64) void delta_kernel(
    const float* __restrict__ qf, const float* __restrict__ kf,
    const float* __restrict__ vf,
    const float* __restrict__ g, const float* __restrict__ beta,
    float* __restrict__ o)
{
  const int blk = blockIdx.x;
  const int bh = blk & 15;     // fastest-varying -> same bh clusters per XCD (bid%8)
  const int jp = blk >> 4;     // 0..127 column pair
  const int b = bh >> 3, h = bh & 7;
  const int lane = threadIdx.x;
  const int r = lane & 31;
  const int j = jp * 2 + (lane >> 5);

  const float* qp = qf + (size_t)(b * T_) * (H_ * DK_) + h * DK_ + r * 4;
  const float* kp = kf + (size_t)(b * T_) * (H_ * DK_) + h * DK_ + r * 4;
  const float* vp = vf + (size_t)(b * T_) * (H_ * DV_) + h * DV_ + j;
  const float* gp = g    + (size_t)(b * T_) * H_ + h;
  const float* bp = beta + (size_t)(b * T_) * H_ + h;
  float*       op = o  + (size_t)(b * T_) * (H_ * DV_) + h * DV_ + j;

  float S0 = 0.f, S1 = 0.f, S2 = 0.f, S3 = 0.f;
  float4 kd = *(const float4*)kp;
  float4 qd = *(const float4*)qp;
  float vv = *vp;
  float bt = *bp;
  float gamma = __expf(*gp);
  for (int t = 0; t < T_; ++t) {
    kp += H_ * DK_; qp += H_ * DK_; vp += H_ * DV_; gp += H_; bp += H_;
    float4 kd2 = *(const float4*)kp;    // prefetch next step (one-row over-read
    float4 qd2 = *(const float4*)qp;    //  at t=T_-1 stays inside ws by layout)
    float vv2 = *vp;
    float bt2 = *bp;
    float gamma2 = __expf(*gp);         // exp off the S-critical-path

    float part = kd.x*S0 + kd.y*S1 + kd.z*S2 + kd.w*S3;
    float dred = red32_dpp(part);            // lane31/63 hold half-sums
    float dot0 = bcast_halves(dred, lane);   // broadcast to own half
    float u = bt * (vv - gamma * dot0);
    S0 = gamma * S0 + kd.x * u;
    S1 = gamma * S1 + kd.y * u;
    S2 = gamma * S2 + kd.z * u;
    S3 = gamma * S3 + kd.w * u;
    float po = qd.x*S0 + qd.y*S1 + qd.z*S2 + qd.w*S3;
    float od = red32_dpp(po);
    if (r == 31) *op = od;                   // lanes 31/63 hold their column's sum
    op += H_ * DV_;
    kd = kd2; qd = qd2; vv = vv2; bt = bt2; gamma = gamma2;
  }
}

// ---------------- gated RMSNorm + silu(gate) -> bf16 ----------------
__global__ __launch_bounds__(256) void post_kernel(
    const float* __restrict__ o, const unsigned short* __restrict__ Y1,
    const float* __restrict__ gw, unsigned short* __restrict__ og)
{
  const int t = blockIdx.x;
  const int tid = threadIdx.x;
  const int e = tid * 8;       // head = tid/32, dv = e&255
  float4 v0 = *(const float4*)(o + (size_t)t * NV_ + e);
  float4 v1 = *(const float4*)(o + (size_t)t * NV_ + e + 4);
  float v[8] = { v0.x, v0.y, v0.z, v0.w, v1.x, v1.y, v1.z, v1.w };
  float ss = 0.f;
  #pragma unroll
  for (int m = 0; m < 8; ++m) ss += v[m] * v[m];
  ss = redsum32(ss);
  float rms = rsqrtf(ss * (1.f / 256.f) + 1e-5f);
  int4 graw = *(const int4*)(Y1 + (size_t)t * N1_ + 4096 + e);
  unsigned int gu[4] = { (unsigned)graw.x, (unsigned)graw.y, (unsigned)graw.z, (unsigned)graw.w };
  float gv[8] = { bflo(gu[0]), bfhi(gu[0]), bflo(gu[1]), bfhi(gu[1]),
                  bflo(gu[2]), bfhi(gu[2]), bflo(gu[3]), bfhi(gu[3]) };
  const int dv = e & 255;
  float res[8];
  #pragma unroll
  for (int m = 0; m < 8; ++m) res[m] = v[m] * rms * gw[dv + m] * siluf(gv[m]);
  int4 outv;
  outv.x = (int)pack2(res[0], res[1]);
  outv.y = (int)pack2(res[2], res[3]);
  outv.z = (int)pack2(res[4], res[5]);
  outv.w = (int)pack2(res[6], res[7]);
  *(int4*)(og + (size_t)t * NV_ + e) = outv;
}

extern "C" void kernel_launch(void* const* d_in, const int* in_sizes, int n_in,
                              void* d_out, int out_size, void* d_ws, size_t ws_size,
                              hipStream_t stream)
{
  (void)in_sizes; (void)n_in; (void)out_size;
  const float* x     = (const float*)d_in[0];
  const float* Wq    = (const float*)d_in[1];
  const float* Wk    = (const float*)d_in[2];
  const float* Wv    = (const float*)d_in[3];
  const float* Wb    = (const float*)d_in[4];
  const float* Wa    = (const float*)d_in[5];
  const float* Wg    = (const float*)d_in[6];
  const float* Wo    = (const float*)d_in[7];
  const float* cq    = (const float*)d_in[8];
  const float* ck    = (const float*)d_in[9];
  const float* cv    = (const float*)d_in[10];
  const float* A_log = (const float*)d_in[11];
  const float* dtb   = (const float*)d_in[12];
  const float* gw    = (const float*)d_in[13];

  // ---- workspace layout with lifetime-based aliasing (peak ~232.5 MiB) ----
  // Region R1 [0, 128MiB):
  //   phase A (cast/transpose/gemm1): xb [0,32MiB) + Wct [32,56MiB)
  //   phase B (conv/delta):           qf [0,32MiB) + kf [32,64MiB) + vf/ov [64,128MiB)
  //   phase C (post/gemm2):           og [0,32MiB)  (qf dead)
  // Then: Wot (8MiB), beta, gl, Y1. Ordering guarantees delta's one-row
  // prefetch over-read of qf/kf/vf/beta/gl lands in the next live buffer.
  char* ws = (char*)d_ws;
  const size_t SZ_XB  = (size_t)BT_ * D_ * 2;       // 32 MiB
  const size_t SZ_WCT = (size_t)N1_ * D_ * 2;       // 24 MiB
  const size_t SZ_QF  = (size_t)BT_ * NQK_ * 4;     // 32 MiB
  const size_t SZ_KF  = (size_t)BT_ * NQK_ * 4;     // 32 MiB
  const size_t SZ_VF  = (size_t)BT_ * NV_ * 4;      // 64 MiB
  const size_t SZ_R1a = SZ_XB + SZ_WCT;
  const size_t SZ_R1b = SZ_QF + SZ_KF + SZ_VF;
  const size_t SZ_R1  = (SZ_R1a > SZ_R1b) ? SZ_R1a : SZ_R1b;
  const size_t SZ_WOT = (size_t)D_ * D_ * 2;        // 8 MiB
  const size_t SZ_BG  = (size_t)BT_ * H_ * 4;       // 256 KiB each
  const size_t SZ_Y1  = (size_t)BT_ * N1_ * 2;      // 96 MiB

  const size_t OFF_WOT  = SZ_R1;
  const size_t OFF_BETA = OFF_WOT + SZ_WOT;
  const size_t OFF_GL   = OFF_BETA + SZ_BG;
  const size_t OFF_Y1   = OFF_GL + SZ_BG;
  const size_t WS_NEEDED = OFF_Y1 + SZ_Y1;
  if (ws_size < WS_NEEDED) return;   // diagnostic: absmax == ref-max ==> ws too small

  unsigned short* xb  = (unsigned short*)(ws);                 // phase A
  unsigned short* Wct = (unsigned short*)(ws + SZ_XB);         // phase A
  float* qf = (float*)(ws);                                    // phase B
  float* kf = (float*)(ws + SZ_QF);                            // phase B
  float* vf = (float*)(ws + SZ_QF + SZ_KF);                    // phase B/C (ov aliases)
  float* ov = vf;
  unsigned short* og  = (unsigned short*)(ws);                 // phase C
  unsigned short* Wot = (unsigned short*)(ws + OFF_WOT);
  float* beta = (float*)(ws + OFF_BETA);
  float* gl   = (float*)(ws + OFF_GL);
  unsigned short* Y1  = (unsigned short*)(ws + OFF_Y1);

  cast_x_kernel<<<(BT_ * D_) / 1024, 256, 0, stream>>>(x, xb);
  dim3 tb(32, 8);
  transpose_cast<<<dim3(1024/32, 2048/32), tb, 0, stream>>>(Wq, Wct, 2048, 1024);
  transpose_cast<<<dim3(1024/32, 2048/32), tb, 0, stream>>>(Wk, Wct + (size_t)1024 * 2048, 2048, 1024);
  transpose_cast<<<dim3(2048/32, 2048/32), tb, 0, stream>>>(Wv, Wct + (size_t)2048 * 2048, 2048, 2048);
  transpose_cast<<<dim3(2048/32, 2048/32), tb, 0, stream>>>(Wg, Wct + (size_t)4096 * 2048, 2048, 2048);
  transpose_cast<<<dim3(2048/32, 2048/32), tb, 0, stream>>>(Wo, Wot, 2048, 2048);

  gemm_kernel<1><<<dim3(N1_/128, BT_/128), 256, 0, stream>>>(xb, Wct, Y1, BT_, N1_, D_);
  beta_g_kernel<<<BT_, 256, 0, stream>>>(x, Wb, Wa, A_log, dtb, beta, gl);
  conv_kernel<<<BT_, 256, 0, stream>>>(Y1, cq, ck, cv, qf, kf, vf);
  delta_kernel<<<B_ * H_ * (DV_/2), 64, 0, stream>>>(qf, kf, vf, gl, beta, ov);
  post_kernel<<<BT_, 256, 0, stream>>>(ov, Y1, gw, og);
  gemm_kernel<0><<<dim3(D_/128, BT_/128), 256, 0, stream>>>(og, Wot, d_out, BT_, D_, D_);
}

// Round 4
// 2011.297 us; speedup vs baseline: 1.6026x; 1.5175x over previous
//
#include <hip/hip_runtime.h>
#include <cstdint>
#include <cstddef>

#define B_ 2
#define T_ 4096
#define D_ 2048
#define H_ 8
#define DK_ 128
#define DV_ 256
#define BT_ (B_*T_)
#define NQK_ 1024
#define NV_ 2048
#define N1_ 6144   // packed: q[0,1024) k[1024,2048) v[2048,4096) gate[4096,6144)

typedef __bf16 bf16x8 __attribute__((ext_vector_type(8)));
typedef float f32x4 __attribute__((ext_vector_type(4)));

#define GAS __attribute__((address_space(1)))
#define LAS __attribute__((address_space(3)))

__device__ __forceinline__ float bfu(unsigned short u) {
  union { unsigned int i; float f; } c; c.i = ((unsigned int)u) << 16; return c.f;
}
__device__ __forceinline__ float bflo(unsigned int u) {
  union { unsigned int i; float f; } c; c.i = u << 16; return c.f;
}
__device__ __forceinline__ float bfhi(unsigned int u) {
  union { unsigned int i; float f; } c; c.i = u & 0xFFFF0000u; return c.f;
}
__device__ __forceinline__ unsigned short f2bf(float f) {
  union { float f; unsigned int i; } c; c.f = f;
  unsigned int x = c.i;
  x += 0x7FFFu + ((x >> 16) & 1u);
  return (unsigned short)(x >> 16);
}
__device__ __forceinline__ unsigned int pack2(float a, float b) {
  return (unsigned int)f2bf(a) | ((unsigned int)f2bf(b) << 16);
}
__device__ __forceinline__ float siluf(float x) { return x / (1.f + __expf(-x)); }
__device__ __forceinline__ float redsum32(float v) {
  #pragma unroll
  for (int m = 16; m >= 1; m >>= 1) v += __shfl_xor(v, m);
  return v;
}
__device__ __forceinline__ void async_copy16(void* lds, const void* gsrc) {
  __builtin_amdgcn_global_load_lds((const GAS unsigned int*)gsrc,
                                   (LAS unsigned int*)lds, 16, 0, 0);
}

// ---- DPP wave reduction helpers (VALU-pipe cross-lane) ----
template<int CTRL>
__device__ __forceinline__ float dpp_add(float x) {
  union { int i; float f; } a, r;
  a.f = x;
  r.i = __builtin_amdgcn_update_dpp(0, a.i, CTRL, 0xF, 0xF, true);
  return x + r.f;
}
// after this: lane31 = sum(lanes 0..31), lane63 = sum(lanes 32..63)
__device__ __forceinline__ float red32_dpp(float x) {
  x = dpp_add<0x111>(x);   // row_shr:1
  x = dpp_add<0x112>(x);   // row_shr:2
  x = dpp_add<0x114>(x);   // row_shr:4
  x = dpp_add<0x118>(x);   // row_shr:8
  x = dpp_add<0x142>(x);   // row_bcast:15
  return x;
}
__device__ __forceinline__ float bcast_halves(float x, int lane) {
  union { int i; float f; } a, lo, hi;
  a.f = x;
  lo.i = __builtin_amdgcn_readlane(a.i, 31);
  hi.i = __builtin_amdgcn_readlane(a.i, 63);
  return (lane & 32) ? hi.f : lo.f;
}

// ---------------- cast x (f32 -> bf16) ----------------
__global__ __launch_bounds__(256) void cast_x_kernel(const float* __restrict__ in,
                                                     unsigned short* __restrict__ out) {
  size_t i = ((size_t)blockIdx.x * 256 + threadIdx.x) * 4;
  float4 v = *(const float4*)(in + i);
  uint2 r;
  r.x = pack2(v.x, v.y);
  r.y = pack2(v.z, v.w);
  *(uint2*)(out + i) = r;
}

// ---------------- transpose + cast weight (f32 [R][C] -> bf16 [C][R]) ----------------
__global__ __launch_bounds__(256) void transpose_cast(const float* __restrict__ in,
                                                      unsigned short* __restrict__ out,
                                                      int R, int Cc) {
  __shared__ float tile[32][33];
  int c0 = blockIdx.x * 32, r0 = blockIdx.y * 32;
  int tx = threadIdx.x, ty = threadIdx.y;  // (32,8)
  #pragma unroll
  for (int i = 0; i < 4; ++i)
    tile[ty + i*8][tx] = in[(size_t)(r0 + ty + i*8) * Cc + c0 + tx];
  __syncthreads();
  #pragma unroll
  for (int i = 0; i < 4; ++i)
    out[(size_t)(c0 + ty + i*8) * R + r0 + tx] = f2bf(tile[tx][ty + i*8]);
}

// ---------------- bf16 MFMA GEMM: C[M,N] = A[M,K] * Bt[N,K]^T ----------------
// 128x128 tile, 4 waves (2x2), 16x16x32 bf16 MFMA, global_load_lds staging.
template<int BF16OUT>
__global__ __launch_bounds__(256) void gemm_kernel(
    const unsigned short* __restrict__ A,   // [M][K] bf16
    const unsigned short* __restrict__ Bt,  // [N][K] bf16
    void* __restrict__ Cout,
    int M, int N, int K)
{
  __shared__ __align__(16) unsigned short As[128][32];
  __shared__ __align__(16) unsigned short Bs[128][32];
  const int tid  = threadIdx.x;
  const int lane = tid & 63;
  const int wave = tid >> 6;
  const int wr = wave >> 1, wc = wave & 1;
  const int row0 = blockIdx.y * 128, col0 = blockIdx.x * 128;
  f32x4 acc[4][4];
  #pragma unroll
  for (int m = 0; m < 4; ++m)
    #pragma unroll
    for (int n = 0; n < 4; ++n)
      acc[m][n] = (f32x4){0.f, 0.f, 0.f, 0.f};

  const int fr = lane & 15;   // row within 16x16 frag
  const int fq = lane >> 4;   // k-quad (8 contiguous k per lane)

  for (int k0 = 0; k0 < K; k0 += 32) {
    #pragma unroll
    for (int i = 0; i < 2; ++i) {
      int c = tid + i * 256;          // chunk id 0..511 -> LDS byte c*16 (linear)
      int r = c >> 2, o = (c & 3) * 8;
      async_copy16(&As[r][o], A  + (size_t)(row0 + r) * K + k0 + o);
      async_copy16(&Bs[r][o], Bt + (size_t)(col0 + r) * K + k0 + o);
    }
    asm volatile("s_waitcnt vmcnt(0)" ::: "memory");
    __syncthreads();
    bf16x8 af[4], bfr[4];
    #pragma unroll
    for (int m = 0; m < 4; ++m)
      af[m] = *(const bf16x8*)&As[wr*64 + m*16 + fr][fq*8];
    #pragma unroll
    for (int n = 0; n < 4; ++n)
      bfr[n] = *(const bf16x8*)&Bs[wc*64 + n*16 + fr][fq*8];
    #pragma unroll
    for (int m = 0; m < 4; ++m)
      #pragma unroll
      for (int n = 0; n < 4; ++n)
        acc[m][n] = __builtin_amdgcn_mfma_f32_16x16x32_bf16(af[m], bfr[n], acc[m][n], 0, 0, 0);
    __syncthreads();
  }
  // C/D layout: col = lane&15, row = (lane>>4)*4 + reg
  const int fc = lane & 15, fg = lane >> 4;
  #pragma unroll
  for (int m = 0; m < 4; ++m)
    #pragma unroll
    for (int n = 0; n < 4; ++n)
      #pragma unroll
      for (int r = 0; r < 4; ++r) {
        size_t idx = (size_t)(row0 + wr*64 + m*16 + fg*4 + r) * N
                   + (col0 + wc*64 + n*16 + fc);
        if (BF16OUT) ((unsigned short*)Cout)[idx] = f2bf(acc[m][n][r]);
        else         ((float*)Cout)[idx]          = acc[m][n][r];
      }
}

// ---------------- beta / gamma projection (f32, N=16) ----------------
// NOTE: stores gamma = exp(g) directly (g only ever used as exp(g)) so the
// delta kernel has no transcendental on its critical path.
__global__ __launch_bounds__(256) void beta_g_kernel(
    const float* __restrict__ x, const float* __restrict__ Wb, const float* __restrict__ Wa,
    const float* __restrict__ A_log, const float* __restrict__ dtb,
    float* __restrict__ beta, float* __restrict__ gmo)
{
  const int t = blockIdx.x;
  const int wave = threadIdx.x >> 6;
  const int lane = threadIdx.x & 63;
  const float* xr = x + (size_t)t * D_;
  float acc[4] = {0.f, 0.f, 0.f, 0.f};
  for (int k = lane; k < D_; k += 64) {
    float xv = xr[k];
    #pragma unroll
    for (int i = 0; i < 4; ++i) {
      int o = wave + 4 * i;                 // 0..7: beta heads, 8..15: a heads
      float w = (o < 8) ? Wb[(size_t)k * 8 + o] : Wa[(size_t)k * 8 + (o - 8)];
      acc[i] += xv * w;
    }
  }
  #pragma unroll
  for (int i = 0; i < 4; ++i) {
    #pragma unroll
    for (int m = 32; m >= 1; m >>= 1) acc[i] += __shfl_xor(acc[i], m);
  }
  if (lane == 0) {
    #pragma unroll
    for (int i = 0; i < 4; ++i) {
      int o = wave + 4 * i;
      if (o < 8) {
        beta[(size_t)t * H_ + o] = 1.f / (1.f + __expf(-acc[i]));
      } else {
        int h = o - 8;
        float z = acc[i] + dtb[h];
        float sp = (z > 20.f) ? z : log1pf(__expf(z));
        gmo[(size_t)t * H_ + h] = __expf(-__expf(A_log[h]) * sp);
      }
    }
  }
}

// ---------------- causal dwconv(W=4) + silu + l2norm ----------------
__global__ __launch_bounds__(256) void conv_kernel(
    const unsigned short* __restrict__ Y1,
    const float* __restrict__ cq, const float* __restrict__ ck, const float* __restrict__ cv,
    float* __restrict__ qf, float* __restrict__ kf, float* __restrict__ vf)
{
  const int t  = blockIdx.x;          // global row (b*T + tt)
  const int tt = t & (T_ - 1);
  const int tid = threadIdx.x;
  const int c4 = tid * 4;
  const int c8 = tid * 8;

  float wqa[4][4], wka[4][4], wva[8][4];
  #pragma unroll
  for (int m = 0; m < 4; ++m) {
    float4 a = *(const float4*)(cq + (size_t)(c4 + m) * 4);
    wqa[m][0] = a.x; wqa[m][1] = a.y; wqa[m][2] = a.z; wqa[m][3] = a.w;
    float4 b = *(const float4*)(ck + (size_t)(c4 + m) * 4);
    wka[m][0] = b.x; wka[m][1] = b.y; wka[m][2] = b.z; wka[m][3] = b.w;
  }
  #pragma unroll
  for (int m = 0; m < 8; ++m) {
    float4 a = *(const float4*)(cv + (size_t)(c8 + m) * 4);
    wva[m][0] = a.x; wva[m][1] = a.y; wva[m][2] = a.z; wva[m][3] = a.w;
  }

  float aq[4] = {0,0,0,0}, ak[4] = {0,0,0,0}, av[8] = {0,0,0,0,0,0,0,0};
  #pragma unroll
  for (int i = 0; i < 4; ++i) {
    if (tt + i >= 3) {      // tap i reads x[t-3+i]
      const unsigned short* row = Y1 + (size_t)(t + i - 3) * N1_;
      ushort4 yq = *(const ushort4*)(row + c4);
      ushort4 yk = *(const ushort4*)(row + NQK_ + c4);
      int4    yv = *(const int4*)(row + 2 * NQK_ + c8);
      float qv[4] = { bfu(yq.x), bfu(yq.y), bfu(yq.z), bfu(yq.w) };
      float kv[4] = { bfu(yk.x), bfu(yk.y), bfu(yk.z), bfu(yk.w) };
      unsigned int vu[4] = { (unsigned)yv.x, (unsigned)yv.y, (unsigned)yv.z, (unsigned)yv.w };
      float vv[8] = { bflo(vu[0]), bfhi(vu[0]), bflo(vu[1]), bfhi(vu[1]),
                      bflo(vu[2]), bfhi(vu[2]), bflo(vu[3]), bfhi(vu[3]) };
      #pragma unroll
      for (int m = 0; m < 4; ++m) { aq[m] += qv[m] * wqa[m][i]; ak[m] += kv[m] * wka[m][i]; }
      #pragma unroll
      for (int m = 0; m < 8; ++m) av[m] += vv[m] * wva[m][i];
    }
  }
  float sq[4], sk[4], ssq = 0.f, ssk = 0.f;
  #pragma unroll
  for (int m = 0; m < 4; ++m) {
    sq[m] = siluf(aq[m]); ssq += sq[m] * sq[m];
    sk[m] = siluf(ak[m]); ssk += sk[m] * sk[m];
  }
  ssq = redsum32(ssq);   // head = tid/32; 32-lane groups align with heads
  ssk = redsum32(ssk);
  float scq = rsqrtf(ssq + 1e-6f) * 0.08838834764831845f;  // * DK^-0.5
  float sck = rsqrtf(ssk + 1e-6f);
  float4 oq = { sq[0]*scq, sq[1]*scq, sq[2]*scq, sq[3]*scq };
  float4 ok = { sk[0]*sck, sk[1]*sck, sk[2]*sck, sk[3]*sck };
  *(float4*)(qf + (size_t)t * NQK_ + c4) = oq;
  *(float4*)(kf + (size_t)t * NQK_ + c4) = ok;
  float4 ov0 = { siluf(av[0]), siluf(av[1]), siluf(av[2]), siluf(av[3]) };
  float4 ov1 = { siluf(av[4]), siluf(av[5]), siluf(av[6]), siluf(av[7]) };
  *(float4*)(vf + (size_t)t * NV_ + c8)     = ov0;
  *(float4*)(vf + (size_t)t * NV_ + c8 + 4) = ov1;
}

// ---------------- gated delta-rule recurrence ----------------
// One wave per (b,h, column-pair). 32 lanes per DV-column, 4 state elems/lane.
// 4 static register slots, prefetch distance 2: loads for step t are issued
// two sub-steps before use, so L2 latency (~200cyc) hides under two compute
// chains. No transcendentals in the loop (gamma precomputed).
// NOTE: o may alias vf — reads of rows t+1/t+2 issue before the write to row
// t lands; columns are disjoint across waves, rows only move forward.
__global__ __launch_bounds__(64) void delta_kernel(
    const float* __restrict__ qf, const float* __restrict__ kf,
    const float* __restrict__ vf,
    const float* __restrict__ gm, const float* __restrict__ beta,
    float* __restrict__ o)
{
  const int blk = blockIdx.x;
  const int bh = blk & 15;     // fastest-varying -> same bh clusters per XCD (bid%8)
  const int jp = blk >> 4;     // 0..127 column pair
  const int b = bh >> 3, h = bh & 7;
  const int lane = threadIdx.x;
  const int r = lane & 31;
  const int j = jp * 2 + (lane >> 5);

  const int SQK = H_ * DK_;    // 1024
  const int SV  = H_ * DV_;    // 2048

  const float* qp = qf + (size_t)(b * T_) * SQK + h * DK_ + r * 4;
  const float* kp = kf + (size_t)(b * T_) * SQK + h * DK_ + r * 4;
  const float* vp = vf + (size_t)(b * T_) * SV + h * DV_ + j;
  const float* gp = gm   + (size_t)(b * T_) * H_ + h;
  const float* bp = beta + (size_t)(b * T_) * H_ + h;
  float*       op = o  + (size_t)(b * T_) * SV + h * DV_ + j;

  float S0 = 0.f, S1 = 0.f, S2 = 0.f, S3 = 0.f;

  // preload slots 0 (t=0) and 1 (t=1)
  float4 kd0 = *(const float4*)kp,         qd0 = *(const float4*)qp;
  float  vv0 = *vp, bt0 = *bp, gm0 = *gp;
  float4 kd1 = *(const float4*)(kp + SQK), qd1 = *(const float4*)(qp + SQK);
  float  vv1 = vp[SV], bt1 = bp[H_], gm1 = gp[H_];
  float4 kd2, qd2, kd3, qd3;
  float  vv2, bt2, gm2, vv3, bt3, gm3;

  // pointers now track the next prefetch row (t+2 at loop top)
  qp += 2 * SQK; kp += 2 * SQK; vp += 2 * SV; gp += 2 * H_; bp += 2 * H_;

#define PREF(SL, ROW) do { \
    kd##SL = *(const float4*)(kp + (ROW) * SQK); \
    qd##SL = *(const float4*)(qp + (ROW) * SQK); \
    vv##SL = vp[(ROW) * SV]; \
    bt##SL = bp[(ROW) * H_]; \
    gm##SL = gp[(ROW) * H_]; \
  } while (0)

#define STEP(SL) do { \
    float part = kd##SL.x*S0 + kd##SL.y*S1 + kd##SL.z*S2 + kd##SL.w*S3; \
    float dred = red32_dpp(part); \
    float dot0 = bcast_halves(dred, lane); \
    float u = bt##SL * (vv##SL - gm##SL * dot0); \
    S0 = gm##SL * S0 + kd##SL.x * u; \
    S1 = gm##SL * S1 + kd##SL.y * u; \
    S2 = gm##SL * S2 + kd##SL.z * u; \
    S3 = gm##SL * S3 + kd##SL.w * u; \
    float po = qd##SL.x*S0 + qd##SL.y*S1 + qd##SL.z*S2 + qd##SL.w*S3; \
    float od = red32_dpp(po); \
    if (r == 31) *op = od; \
    op += SV; \
  } while (0)

  for (int t = 0; t < T_; t += 4) {
    PREF(2, 0); STEP(0);
    PREF(3, 1); STEP(1);
    PREF(0, 2); STEP(2);
    PREF(1, 3); STEP(3);
    qp += 4 * SQK; kp += 4 * SQK; vp += 4 * SV; gp += 4 * H_; bp += 4 * H_;
  }
#undef PREF
#undef STEP
}

// ---------------- gated RMSNorm + silu(gate) -> bf16 ----------------
__global__ __launch_bounds__(256) void post_kernel(
    const float* __restrict__ o, const unsigned short* __restrict__ Y1,
    const float* __restrict__ gw, unsigned short* __restrict__ og)
{
  const int t = blockIdx.x;
  const int tid = threadIdx.x;
  const int e = tid * 8;       // head = tid/32, dv = e&255
  float4 v0 = *(const float4*)(o + (size_t)t * NV_ + e);
  float4 v1 = *(const float4*)(o + (size_t)t * NV_ + e + 4);
  float v[8] = { v0.x, v0.y, v0.z, v0.w, v1.x, v1.y, v1.z, v1.w };
  float ss = 0.f;
  #pragma unroll
  for (int m = 0; m < 8; ++m) ss += v[m] * v[m];
  ss = redsum32(ss);
  float rms = rsqrtf(ss * (1.f / 256.f) + 1e-5f);
  int4 graw = *(const int4*)(Y1 + (size_t)t * N1_ + 4096 + e);
  unsigned int gu[4] = { (unsigned)graw.x, (unsigned)graw.y, (unsigned)graw.z, (unsigned)graw.w };
  float gv[8] = { bflo(gu[0]), bfhi(gu[0]), bflo(gu[1]), bfhi(gu[1]),
                  bflo(gu[2]), bfhi(gu[2]), bflo(gu[3]), bfhi(gu[3]) };
  const int dv = e & 255;
  float res[8];
  #pragma unroll
  for (int m = 0; m < 8; ++m) res[m] = v[m] * rms * gw[dv + m] * siluf(gv[m]);
  int4 outv;
  outv.x = (int)pack2(res[0], res[1]);
  outv.y = (int)pack2(res[2], res[3]);
  outv.z = (int)pack2(res[4], res[5]);
  outv.w = (int)pack2(res[6], res[7]);
  *(int4*)(og + (size_t)t * NV_ + e) = outv;
}

extern "C" void kernel_launch(void* const* d_in, const int* in_sizes, int n_in,
                              void* d_out, int out_size, void* d_ws, size_t ws_size,
                              hipStream_t stream)
{
  (void)in_sizes; (void)n_in; (void)out_size;
  const float* x     = (const float*)d_in[0];
  const float* Wq    = (const float*)d_in[1];
  const float* Wk    = (const float*)d_in[2];
  const float* Wv    = (const float*)d_in[3];
  const float* Wb    = (const float*)d_in[4];
  const float* Wa    = (const float*)d_in[5];
  const float* Wg    = (const float*)d_in[6];
  const float* Wo    = (const float*)d_in[7];
  const float* cq    = (const float*)d_in[8];
  const float* ck    = (const float*)d_in[9];
  const float* cv    = (const float*)d_in[10];
  const float* A_log = (const float*)d_in[11];
  const float* dtb   = (const float*)d_in[12];
  const float* gw    = (const float*)d_in[13];

  // ---- workspace layout with lifetime-based aliasing (peak ~232.5 MiB) ----
  // Region R1 [0, 128MiB):
  //   phase A (cast/transpose/gemm1): xb [0,32MiB) + Wct [32,56MiB)
  //   phase B (conv/delta):           qf [0,32MiB) + kf [32,64MiB) + vf/ov [64,128MiB)
  //   phase C (post/gemm2):           og [0,32MiB)  (qf dead)
  // Then: Wot (8MiB), beta, gl, Y1. Ordering guarantees delta's two-row
  // prefetch over-read of qf/kf/vf/beta/gl lands in the next live buffer.
  char* ws = (char*)d_ws;
  const size_t SZ_XB  = (size_t)BT_ * D_ * 2;       // 32 MiB
  const size_t SZ_WCT = (size_t)N1_ * D_ * 2;       // 24 MiB
  const size_t SZ_QF  = (size_t)BT_ * NQK_ * 4;     // 32 MiB
  const size_t SZ_KF  = (size_t)BT_ * NQK_ * 4;     // 32 MiB
  const size_t SZ_VF  = (size_t)BT_ * NV_ * 4;      // 64 MiB
  const size_t SZ_R1a = SZ_XB + SZ_WCT;
  const size_t SZ_R1b = SZ_QF + SZ_KF + SZ_VF;
  const size_t SZ_R1  = (SZ_R1a > SZ_R1b) ? SZ_R1a : SZ_R1b;
  const size_t SZ_WOT = (size_t)D_ * D_ * 2;        // 8 MiB
  const size_t SZ_BG  = (size_t)BT_ * H_ * 4;       // 256 KiB each
  const size_t SZ_Y1  = (size_t)BT_ * N1_ * 2;      // 96 MiB

  const size_t OFF_WOT  = SZ_R1;
  const size_t OFF_BETA = OFF_WOT + SZ_WOT;
  const size_t OFF_GL   = OFF_BETA + SZ_BG;
  const size_t OFF_Y1   = OFF_GL + SZ_BG;
  const size_t WS_NEEDED = OFF_Y1 + SZ_Y1;
  if (ws_size < WS_NEEDED) return;   // diagnostic: absmax == ref-max ==> ws too small

  unsigned short* xb  = (unsigned short*)(ws);                 // phase A
  unsigned short* Wct = (unsigned short*)(ws + SZ_XB);         // phase A
  float* qf = (float*)(ws);                                    // phase B
  float* kf = (float*)(ws + SZ_QF);                            // phase B
  float* vf = (float*)(ws + SZ_QF + SZ_KF);                    // phase B/C (ov aliases)
  float* ov = vf;
  unsigned short* og  = (unsigned short*)(ws);                 // phase C
  unsigned short* Wot = (unsigned short*)(ws + OFF_WOT);
  float* beta = (float*)(ws + OFF_BETA);
  float* gl   = (float*)(ws + OFF_GL);
  unsigned short* Y1  = (unsigned short*)(ws + OFF_Y1);

  cast_x_kernel<<<(BT_ * D_) / 1024, 256, 0, stream>>>(x, xb);
  dim3 tb(32, 8);
  transpose_cast<<<dim3(1024/32, 2048/32), tb, 0, stream>>>(Wq, Wct, 2048, 1024);
  transpose_cast<<<dim3(1024/32, 2048/32), tb, 0, stream>>>(Wk, Wct + (size_t)1024 * 2048, 2048, 1024);
  transpose_cast<<<dim3(2048/32, 2048/32), tb, 0, stream>>>(Wv, Wct + (size_t)2048 * 2048, 2048, 2048);
  transpose_cast<<<dim3(2048/32, 2048/32), tb, 0, stream>>>(Wg, Wct + (size_t)4096 * 2048, 2048, 2048);
  transpose_cast<<<dim3(2048/32, 2048/32), tb, 0, stream>>>(Wo, Wot, 2048, 2048);

  gemm_kernel<1><<<dim3(N1_/128, BT_/128), 256, 0, stream>>>(xb, Wct, Y1, BT_, N1_, D_);
  beta_g_kernel<<<BT_, 256, 0, stream>>>(x, Wb, Wa, A_log, dtb, beta, gl);
  conv_kernel<<<BT_, 256, 0, stream>>>(Y1, cq, ck, cv, qf, kf, vf);
  delta_kernel<<<B_ * H_ * (DV_/2), 64, 0, stream>>>(qf, kf, vf, gl, beta, ov);
  post_kernel<<<BT_, 256, 0, stream>>>(ov, Y1, gw, og);
  gemm_kernel<0><<<dim3(D_/128, BT_/128), 256, 0, stream>>>(og, Wot, d_out, BT_, D_, D_);
}

// Round 5
// 1957.992 us; speedup vs baseline: 1.6462x; 1.0272x over previous
//
#include <hip/hip_runtime.h>
#include <cstdint>
#include <cstddef>

#define B_ 2
#define T_ 4096
#define D_ 2048
#define H_ 8
#define DK_ 128
#define DV_ 256
#define BT_ (B_*T_)
#define NQK_ 1024
#define NV_ 2048
#define N1_ 6144   // packed: q[0,1024) k[1024,2048) v[2048,4096) gate[4096,6144)

typedef __bf16 bf16x8 __attribute__((ext_vector_type(8)));
typedef float f32x4 __attribute__((ext_vector_type(4)));

#define GAS __attribute__((address_space(1)))
#define LAS __attribute__((address_space(3)))

__device__ __forceinline__ float bfu(unsigned short u) {
  union { unsigned int i; float f; } c; c.i = ((unsigned int)u) << 16; return c.f;
}
__device__ __forceinline__ float bflo(unsigned int u) {
  union { unsigned int i; float f; } c; c.i = u << 16; return c.f;
}
__device__ __forceinline__ float bfhi(unsigned int u) {
  union { unsigned int i; float f; } c; c.i = u & 0xFFFF0000u; return c.f;
}
__device__ __forceinline__ unsigned short f2bf(float f) {
  union { float f; unsigned int i; } c; c.f = f;
  unsigned int x = c.i;
  x += 0x7FFFu + ((x >> 16) & 1u);
  return (unsigned short)(x >> 16);
}
__device__ __forceinline__ unsigned int pack2(float a, float b) {
  return (unsigned int)f2bf(a) | ((unsigned int)f2bf(b) << 16);
}
__device__ __forceinline__ float siluf(float x) { return x / (1.f + __expf(-x)); }
__device__ __forceinline__ float redsum32(float v) {
  #pragma unroll
  for (int m = 16; m >= 1; m >>= 1) v += __shfl_xor(v, m);
  return v;
}
__device__ __forceinline__ void async_copy16(void* lds, const void* gsrc) {
  __builtin_amdgcn_global_load_lds((const GAS unsigned int*)gsrc,
                                   (LAS unsigned int*)lds, 16, 0, 0);
}

// ---- DPP helpers ----
template<int CTRL>
__device__ __forceinline__ float dpp_add(float x) {
  union { int i; float f; } a, r;
  a.f = x;
  r.i = __builtin_amdgcn_update_dpp(0, a.i, CTRL, 0xF, 0xF, true);
  return x + r.f;
}
// rotate-based reduction within each 16-lane row: EVERY lane gets the row sum
// (no readlane/broadcast needed).
__device__ __forceinline__ float red16_ror(float x) {
  x = dpp_add<0x121>(x);   // row_ror:1
  x = dpp_add<0x122>(x);   // row_ror:2
  x = dpp_add<0x124>(x);   // row_ror:4
  x = dpp_add<0x128>(x);   // row_ror:8
  return x;
}

// ---------------- cast x (f32 -> bf16) ----------------
__global__ __launch_bounds__(256) void cast_x_kernel(const float* __restrict__ in,
                                                     unsigned short* __restrict__ out) {
  size_t i = ((size_t)blockIdx.x * 256 + threadIdx.x) * 4;
  float4 v = *(const float4*)(in + i);
  uint2 r;
  r.x = pack2(v.x, v.y);
  r.y = pack2(v.z, v.w);
  *(uint2*)(out + i) = r;
}

// ---------------- transpose + cast weight (f32 [R][C] -> bf16 [C][R]) ----------------
__global__ __launch_bounds__(256) void transpose_cast(const float* __restrict__ in,
                                                      unsigned short* __restrict__ out,
                                                      int R, int Cc) {
  __shared__ float tile[32][33];
  int c0 = blockIdx.x * 32, r0 = blockIdx.y * 32;
  int tx = threadIdx.x, ty = threadIdx.y;  // (32,8)
  #pragma unroll
  for (int i = 0; i < 4; ++i)
    tile[ty + i*8][tx] = in[(size_t)(r0 + ty + i*8) * Cc + c0 + tx];
  __syncthreads();
  #pragma unroll
  for (int i = 0; i < 4; ++i)
    out[(size_t)(c0 + ty + i*8) * R + r0 + tx] = f2bf(tile[tx][ty + i*8]);
}

// ---------------- bf16 MFMA GEMM: C[M,N] = A[M,K] * Bt[N,K]^T ----------------
template<int BF16OUT>
__global__ __launch_bounds__(256) void gemm_kernel(
    const unsigned short* __restrict__ A,   // [M][K] bf16
    const unsigned short* __restrict__ Bt,  // [N][K] bf16
    void* __restrict__ Cout,
    int M, int N, int K)
{
  __shared__ __align__(16) unsigned short As[128][32];
  __shared__ __align__(16) unsigned short Bs[128][32];
  const int tid  = threadIdx.x;
  const int lane = tid & 63;
  const int wave = tid >> 6;
  const int wr = wave >> 1, wc = wave & 1;
  const int row0 = blockIdx.y * 128, col0 = blockIdx.x * 128;
  f32x4 acc[4][4];
  #pragma unroll
  for (int m = 0; m < 4; ++m)
    #pragma unroll
    for (int n = 0; n < 4; ++n)
      acc[m][n] = (f32x4){0.f, 0.f, 0.f, 0.f};

  const int fr = lane & 15;   // row within 16x16 frag
  const int fq = lane >> 4;   // k-quad (8 contiguous k per lane)

  for (int k0 = 0; k0 < K; k0 += 32) {
    #pragma unroll
    for (int i = 0; i < 2; ++i) {
      int c = tid + i * 256;          // chunk id 0..511 -> LDS byte c*16 (linear)
      int r = c >> 2, o = (c & 3) * 8;
      async_copy16(&As[r][o], A  + (size_t)(row0 + r) * K + k0 + o);
      async_copy16(&Bs[r][o], Bt + (size_t)(col0 + r) * K + k0 + o);
    }
    asm volatile("s_waitcnt vmcnt(0)" ::: "memory");
    __syncthreads();
    bf16x8 af[4], bfr[4];
    #pragma unroll
    for (int m = 0; m < 4; ++m)
      af[m] = *(const bf16x8*)&As[wr*64 + m*16 + fr][fq*8];
    #pragma unroll
    for (int n = 0; n < 4; ++n)
      bfr[n] = *(const bf16x8*)&Bs[wc*64 + n*16 + fr][fq*8];
    #pragma unroll
    for (int m = 0; m < 4; ++m)
      #pragma unroll
      for (int n = 0; n < 4; ++n)
        acc[m][n] = __builtin_amdgcn_mfma_f32_16x16x32_bf16(af[m], bfr[n], acc[m][n], 0, 0, 0);
    __syncthreads();
  }
  // C/D layout: col = lane&15, row = (lane>>4)*4 + reg
  const int fc = lane & 15, fg = lane >> 4;
  #pragma unroll
  for (int m = 0; m < 4; ++m)
    #pragma unroll
    for (int n = 0; n < 4; ++n)
      #pragma unroll
      for (int r = 0; r < 4; ++r) {
        size_t idx = (size_t)(row0 + wr*64 + m*16 + fg*4 + r) * N
                   + (col0 + wc*64 + n*16 + fc);
        if (BF16OUT) ((unsigned short*)Cout)[idx] = f2bf(acc[m][n][r]);
        else         ((float*)Cout)[idx]          = acc[m][n][r];
      }
}

// ---------------- beta / gamma projection (f32, N=16) ----------------
// Stores interleaved (beta, gamma=exp(g)) pairs so delta does ONE float2 load
// per step and has no transcendental on its critical path.
__global__ __launch_bounds__(256) void beta_g_kernel(
    const float* __restrict__ x, const float* __restrict__ Wb, const float* __restrict__ Wa,
    const float* __restrict__ A_log, const float* __restrict__ dtb,
    float* __restrict__ bg)
{
  const int t = blockIdx.x;
  const int wave = threadIdx.x >> 6;
  const int lane = threadIdx.x & 63;
  const float* xr = x + (size_t)t * D_;
  float acc[4] = {0.f, 0.f, 0.f, 0.f};
  for (int k = lane; k < D_; k += 64) {
    float xv = xr[k];
    #pragma unroll
    for (int i = 0; i < 4; ++i) {
      int o = wave + 4 * i;                 // 0..7: beta heads, 8..15: a heads
      float w = (o < 8) ? Wb[(size_t)k * 8 + o] : Wa[(size_t)k * 8 + (o - 8)];
      acc[i] += xv * w;
    }
  }
  #pragma unroll
  for (int i = 0; i < 4; ++i) {
    #pragma unroll
    for (int m = 32; m >= 1; m >>= 1) acc[i] += __shfl_xor(acc[i], m);
  }
  if (lane == 0) {
    #pragma unroll
    for (int i = 0; i < 4; ++i) {
      int o = wave + 4 * i;
      if (o < 8) {
        bg[((size_t)t * H_ + o) * 2] = 1.f / (1.f + __expf(-acc[i]));
      } else {
        int h = o - 8;
        float z = acc[i] + dtb[h];
        float sp = (z > 20.f) ? z : log1pf(__expf(z));
        bg[((size_t)t * H_ + h) * 2 + 1] = __expf(-__expf(A_log[h]) * sp);
      }
    }
  }
}

// ---------------- causal dwconv(W=4) + silu + l2norm ----------------
__global__ __launch_bounds__(256) void conv_kernel(
    const unsigned short* __restrict__ Y1,
    const float* __restrict__ cq, const float* __restrict__ ck, const float* __restrict__ cv,
    float* __restrict__ qf, float* __restrict__ kf, float* __restrict__ vf)
{
  const int t  = blockIdx.x;          // global row (b*T + tt)
  const int tt = t & (T_ - 1);
  const int tid = threadIdx.x;
  const int c4 = tid * 4;
  const int c8 = tid * 8;

  float wqa[4][4], wka[4][4], wva[8][4];
  #pragma unroll
  for (int m = 0; m < 4; ++m) {
    float4 a = *(const float4*)(cq + (size_t)(c4 + m) * 4);
    wqa[m][0] = a.x; wqa[m][1] = a.y; wqa[m][2] = a.z; wqa[m][3] = a.w;
    float4 b = *(const float4*)(ck + (size_t)(c4 + m) * 4);
    wka[m][0] = b.x; wka[m][1] = b.y; wka[m][2] = b.z; wka[m][3] = b.w;
  }
  #pragma unroll
  for (int m = 0; m < 8; ++m) {
    float4 a = *(const float4*)(cv + (size_t)(c8 + m) * 4);
    wva[m][0] = a.x; wva[m][1] = a.y; wva[m][2] = a.z; wva[m][3] = a.w;
  }

  float aq[4] = {0,0,0,0}, ak[4] = {0,0,0,0}, av[8] = {0,0,0,0,0,0,0,0};
  #pragma unroll
  for (int i = 0; i < 4; ++i) {
    if (tt + i >= 3) {      // tap i reads x[t-3+i]
      const unsigned short* row = Y1 + (size_t)(t + i - 3) * N1_;
      ushort4 yq = *(const ushort4*)(row + c4);
      ushort4 yk = *(const ushort4*)(row + NQK_ + c4);
      int4    yv = *(const int4*)(row + 2 * NQK_ + c8);
      float qv[4] = { bfu(yq.x), bfu(yq.y), bfu(yq.z), bfu(yq.w) };
      float kv[4] = { bfu(yk.x), bfu(yk.y), bfu(yk.z), bfu(yk.w) };
      unsigned int vu[4] = { (unsigned)yv.x, (unsigned)yv.y, (unsigned)yv.z, (unsigned)yv.w };
      float vv[8] = { bflo(vu[0]), bfhi(vu[0]), bflo(vu[1]), bfhi(vu[1]),
                      bflo(vu[2]), bfhi(vu[2]), bflo(vu[3]), bfhi(vu[3]) };
      #pragma unroll
      for (int m = 0; m < 4; ++m) { aq[m] += qv[m] * wqa[m][i]; ak[m] += kv[m] * wka[m][i]; }
      #pragma unroll
      for (int m = 0; m < 8; ++m) av[m] += vv[m] * wva[m][i];
    }
  }
  float sq[4], sk[4], ssq = 0.f, ssk = 0.f;
  #pragma unroll
  for (int m = 0; m < 4; ++m) {
    sq[m] = siluf(aq[m]); ssq += sq[m] * sq[m];
    sk[m] = siluf(ak[m]); ssk += sk[m] * sk[m];
  }
  ssq = redsum32(ssq);   // head = tid/32; 32-lane groups align with heads
  ssk = redsum32(ssk);
  float scq = rsqrtf(ssq + 1e-6f) * 0.08838834764831845f;  // * DK^-0.5
  float sck = rsqrtf(ssk + 1e-6f);
  float4 oq = { sq[0]*scq, sq[1]*scq, sq[2]*scq, sq[3]*scq };
  float4 ok = { sk[0]*sck, sk[1]*sck, sk[2]*sck, sk[3]*sck };
  *(float4*)(qf + (size_t)t * NQK_ + c4) = oq;
  *(float4*)(kf + (size_t)t * NQK_ + c4) = ok;
  float4 ov0 = { siluf(av[0]), siluf(av[1]), siluf(av[2]), siluf(av[3]) };
  float4 ov1 = { siluf(av[4]), siluf(av[5]), siluf(av[6]), siluf(av[7]) };
  *(float4*)(vf + (size_t)t * NV_ + c8)     = ov0;
  *(float4*)(vf + (size_t)t * NV_ + c8 + 4) = ov1;
}

// ---------------- gated delta-rule recurrence ----------------
// 16-lane groups: each group owns one DV-column, 8 state elems/lane (DK=128).
// 4 columns per wave, 1024 blocks. ror-based DPP reduction leaves the full
// sum in EVERY lane (no readlane broadcast). 8 register slots = prefetch
// distance 8 (~1000+ cyc) to cover HBM latency on the vf stream.
// Over-read audit (rows up to T+7): qf->kf, kf->vf, vf->Wot(+56KB, read-only),
// bg->Y1 — all inside ws, read-only. o aliases vf: reads stay >=8 rows ahead
// of the store row; columns disjoint across waves.
__global__ __launch_bounds__(64) void delta_kernel(
    const float* __restrict__ qf, const float* __restrict__ kf,
    const float* __restrict__ vf, const float* __restrict__ bg,
    float* __restrict__ o)
{
  const int blk = blockIdx.x;
  const int bh = blk & 15;     // fastest-varying -> same bh clusters per XCD
  const int jq = blk >> 4;     // 0..63 column quad
  const int b = bh >> 3, h = bh & 7;
  const int lane = threadIdx.x;
  const int r = lane & 15;
  const int j = jq * 4 + (lane >> 4);

  const int SQK = H_ * DK_;    // 1024
  const int SV  = H_ * DV_;    // 2048

  const float* qp = qf + (size_t)(b * T_) * SQK + h * DK_ + r * 8;
  const float* kp = kf + (size_t)(b * T_) * SQK + h * DK_ + r * 8;
  const float* vp = vf + (size_t)(b * T_) * SV + h * DV_ + j;
  const float* gp = bg + ((size_t)(b * T_) * H_ + h) * 2;
  float*       op = o  + (size_t)(b * T_) * SV + h * DV_ + j;

  float4 Sa = {0,0,0,0}, Sb = {0,0,0,0};

  float4 ka0,kb0,qa0,qb0, ka1,kb1,qa1,qb1, ka2,kb2,qa2,qb2, ka3,kb3,qa3,qb3,
         ka4,kb4,qa4,qb4, ka5,kb5,qa5,qb5, ka6,kb6,qa6,qb6, ka7,kb7,qa7,qb7;
  float  vv0,vv1,vv2,vv3,vv4,vv5,vv6,vv7;
  float2 bgv0,bgv1,bgv2,bgv3,bgv4,bgv5,bgv6,bgv7;

#define PREF(SL, ROW) do { \
    ka##SL = *(const float4*)(kp + (ROW) * SQK); \
    kb##SL = *(const float4*)(kp + (ROW) * SQK + 4); \
    qa##SL = *(const float4*)(qp + (ROW) * SQK); \
    qb##SL = *(const float4*)(qp + (ROW) * SQK + 4); \
    vv##SL = vp[(ROW) * SV]; \
    bgv##SL = *(const float2*)(gp + (ROW) * (H_ * 2)); \
  } while (0)

#define STEP(SL) do { \
    float p0 = ka##SL.x*Sa.x, p1 = ka##SL.y*Sa.y, p2 = ka##SL.z*Sa.z, p3 = ka##SL.w*Sa.w; \
    float p4 = kb##SL.x*Sb.x, p5 = kb##SL.y*Sb.y, p6 = kb##SL.z*Sb.z, p7 = kb##SL.w*Sb.w; \
    float part = ((p0 + p1) + (p2 + p3)) + ((p4 + p5) + (p6 + p7)); \
    float dot = red16_ror(part); \
    float gm = bgv##SL.y; \
    float u = bgv##SL.x * fmaf(-gm, dot, vv##SL); \
    Sa.x = fmaf(gm, Sa.x, ka##SL.x * u); \
    Sa.y = fmaf(gm, Sa.y, ka##SL.y * u); \
    Sa.z = fmaf(gm, Sa.z, ka##SL.z * u); \
    Sa.w = fmaf(gm, Sa.w, ka##SL.w * u); \
    Sb.x = fmaf(gm, Sb.x, kb##SL.x * u); \
    Sb.y = fmaf(gm, Sb.y, kb##SL.y * u); \
    Sb.z = fmaf(gm, Sb.z, kb##SL.z * u); \
    Sb.w = fmaf(gm, Sb.w, kb##SL.w * u); \
    float o0 = qa##SL.x*Sa.x, o1 = qa##SL.y*Sa.y, o2 = qa##SL.z*Sa.z, o3 = qa##SL.w*Sa.w; \
    float o4 = qb##SL.x*Sb.x, o5 = qb##SL.y*Sb.y, o6 = qb##SL.z*Sb.z, o7 = qb##SL.w*Sb.w; \
    float pov = ((o0 + o1) + (o2 + o3)) + ((o4 + o5) + (o6 + o7)); \
    float od = red16_ror(pov); \
    if (r == 0) *op = od; \
    op += SV; \
  } while (0)

  // prologue: rows 0..7 into slots 0..7
  PREF(0,0); PREF(1,1); PREF(2,2); PREF(3,3);
  PREF(4,4); PREF(5,5); PREF(6,6); PREF(7,7);
  qp += 8 * SQK; kp += 8 * SQK; vp += 8 * SV; gp += 8 * (H_ * 2);

  for (int t = 0; t < T_; t += 8) {
    STEP(0); PREF(0,0);
    STEP(1); PREF(1,1);
    STEP(2); PREF(2,2);
    STEP(3); PREF(3,3);
    STEP(4); PREF(4,4);
    STEP(5); PREF(5,5);
    STEP(6); PREF(6,6);
    STEP(7); PREF(7,7);
    qp += 8 * SQK; kp += 8 * SQK; vp += 8 * SV; gp += 8 * (H_ * 2);
  }
#undef PREF
#undef STEP
}

// ---------------- gated RMSNorm + silu(gate) -> bf16 ----------------
__global__ __launch_bounds__(256) void post_kernel(
    const float* __restrict__ o, const unsigned short* __restrict__ Y1,
    const float* __restrict__ gw, unsigned short* __restrict__ og)
{
  const int t = blockIdx.x;
  const int tid = threadIdx.x;
  const int e = tid * 8;       // head = tid/32, dv = e&255
  float4 v0 = *(const float4*)(o + (size_t)t * NV_ + e);
  float4 v1 = *(const float4*)(o + (size_t)t * NV_ + e + 4);
  float v[8] = { v0.x, v0.y, v0.z, v0.w, v1.x, v1.y, v1.z, v1.w };
  float ss = 0.f;
  #pragma unroll
  for (int m = 0; m < 8; ++m) ss += v[m] * v[m];
  ss = redsum32(ss);
  float rms = rsqrtf(ss * (1.f / 256.f) + 1e-5f);
  int4 graw = *(const int4*)(Y1 + (size_t)t * N1_ + 4096 + e);
  unsigned int gu[4] = { (unsigned)graw.x, (unsigned)graw.y, (unsigned)graw.z, (unsigned)graw.w };
  float gv[8] = { bflo(gu[0]), bfhi(gu[0]), bflo(gu[1]), bfhi(gu[1]),
                  bflo(gu[2]), bfhi(gu[2]), bflo(gu[3]), bfhi(gu[3]) };
  const int dv = e & 255;
  float res[8];
  #pragma unroll
  for (int m = 0; m < 8; ++m) res[m] = v[m] * rms * gw[dv + m] * siluf(gv[m]);
  int4 outv;
  outv.x = (int)pack2(res[0], res[1]);
  outv.y = (int)pack2(res[2], res[3]);
  outv.z = (int)pack2(res[4], res[5]);
  outv.w = (int)pack2(res[6], res[7]);
  *(int4*)(og + (size_t)t * NV_ + e) = outv;
}

extern "C" void kernel_launch(void* const* d_in, const int* in_sizes, int n_in,
                              void* d_out, int out_size, void* d_ws, size_t ws_size,
                              hipStream_t stream)
{
  (void)in_sizes; (void)n_in; (void)out_size;
  const float* x     = (const float*)d_in[0];
  const float* Wq    = (const float*)d_in[1];
  const float* Wk    = (const float*)d_in[2];
  const float* Wv    = (const float*)d_in[3];
  const float* Wb    = (const float*)d_in[4];
  const float* Wa    = (const float*)d_in[5];
  const float* Wg    = (const float*)d_in[6];
  const float* Wo    = (const float*)d_in[7];
  const float* cq    = (const float*)d_in[8];
  const float* ck    = (const float*)d_in[9];
  const float* cv    = (const float*)d_in[10];
  const float* A_log = (const float*)d_in[11];
  const float* dtb   = (const float*)d_in[12];
  const float* gw    = (const float*)d_in[13];

  // ---- workspace layout with lifetime-based aliasing (peak ~232.5 MiB) ----
  // Region R1 [0, 128MiB):
  //   phase A (cast/transpose/gemm1): xb [0,32MiB) + Wct [32,56MiB)
  //   phase B (conv/delta):           qf [0,32MiB) + kf [32,64MiB) + vf/ov [64,128MiB)
  //   phase C (post/gemm2):           og [0,32MiB)  (qf dead)
  // Then: Wot (8MiB), bg (512KiB), Y1 (96MiB). Ordering guarantees delta's
  // 8-row prefetch over-read of qf/kf/vf/bg lands in the next live buffer.
  char* ws = (char*)d_ws;
  const size_t SZ_XB  = (size_t)BT_ * D_ * 2;       // 32 MiB
  const size_t SZ_WCT = (size_t)N1_ * D_ * 2;       // 24 MiB
  const size_t SZ_QF  = (size_t)BT_ * NQK_ * 4;     // 32 MiB
  const size_t SZ_KF  = (size_t)BT_ * NQK_ * 4;     // 32 MiB
  const size_t SZ_VF  = (size_t)BT_ * NV_ * 4;      // 64 MiB
  const size_t SZ_R1a = SZ_XB + SZ_WCT;
  const size_t SZ_R1b = SZ_QF + SZ_KF + SZ_VF;
  const size_t SZ_R1  = (SZ_R1a > SZ_R1b) ? SZ_R1a : SZ_R1b;
  const size_t SZ_WOT = (size_t)D_ * D_ * 2;        // 8 MiB
  const size_t SZ_BG  = (size_t)BT_ * H_ * 8;       // 512 KiB (float2)
  const size_t SZ_Y1  = (size_t)BT_ * N1_ * 2;      // 96 MiB

  const size_t OFF_WOT = SZ_R1;
  const size_t OFF_BG  = OFF_WOT + SZ_WOT;
  const size_t OFF_Y1  = OFF_BG + SZ_BG;
  const size_t WS_NEEDED = OFF_Y1 + SZ_Y1;
  if (ws_size < WS_NEEDED) return;   // diagnostic: absmax == ref-max ==> ws too small

  unsigned short* xb  = (unsigned short*)(ws);                 // phase A
  unsigned short* Wct = (unsigned short*)(ws + SZ_XB);         // phase A
  float* qf = (float*)(ws);                                    // phase B
  float* kf = (float*)(ws + SZ_QF);                            // phase B
  float* vf = (float*)(ws + SZ_QF + SZ_KF);                    // phase B/C (ov aliases)
  float* ov = vf;
  unsigned short* og  = (unsigned short*)(ws);                 // phase C
  unsigned short* Wot = (unsigned short*)(ws + OFF_WOT);
  float* bg   = (float*)(ws + OFF_BG);
  unsigned short* Y1  = (unsigned short*)(ws + OFF_Y1);

  cast_x_kernel<<<(BT_ * D_) / 1024, 256, 0, stream>>>(x, xb);
  dim3 tb(32, 8);
  transpose_cast<<<dim3(1024/32, 2048/32), tb, 0, stream>>>(Wq, Wct, 2048, 1024);
  transpose_cast<<<dim3(1024/32, 2048/32), tb, 0, stream>>>(Wk, Wct + (size_t)1024 * 2048, 2048, 1024);
  transpose_cast<<<dim3(2048/32, 2048/32), tb, 0, stream>>>(Wv, Wct + (size_t)2048 * 2048, 2048, 2048);
  transpose_cast<<<dim3(2048/32, 2048/32), tb, 0, stream>>>(Wg, Wct + (size_t)4096 * 2048, 2048, 2048);
  transpose_cast<<<dim3(2048/32, 2048/32), tb, 0, stream>>>(Wo, Wot, 2048, 2048);

  gemm_kernel<1><<<dim3(N1_/128, BT_/128), 256, 0, stream>>>(xb, Wct, Y1, BT_, N1_, D_);
  beta_g_kernel<<<BT_, 256, 0, stream>>>(x, Wb, Wa, A_log, dtb, bg);
  conv_kernel<<<BT_, 256, 0, stream>>>(Y1, cq, ck, cv, qf, kf, vf);
  delta_kernel<<<B_ * H_ * (DV_/4), 64, 0, stream>>>(qf, kf, vf, bg, ov);
  post_kernel<<<BT_, 256, 0, stream>>>(ov, Y1, gw, og);
  gemm_kernel<0><<<dim3(D_/128, BT_/128), 256, 0, stream>>>(og, Wot, d_out, BT_, D_, D_);
}

// Round 6
// 1944.648 us; speedup vs baseline: 1.6575x; 1.0069x over previous
//
#include <hip/hip_runtime.h>
#include <cstdint>
#include <cstddef>

#define B_ 2
#define T_ 4096
#define D_ 2048
#define H_ 8
#define DK_ 128
#define DV_ 256
#define BT_ (B_*T_)
#define NQK_ 1024
#define NV_ 2048
#define N1_ 6144   // packed: q[0,1024) k[1024,2048) v[2048,4096) gate[4096,6144)

typedef __bf16 bf16x8 __attribute__((ext_vector_type(8)));
typedef float f32x4 __attribute__((ext_vector_type(4)));

#define GAS __attribute__((address_space(1)))
#define LAS __attribute__((address_space(3)))

__device__ __forceinline__ float bfu(unsigned short u) {
  union { unsigned int i; float f; } c; c.i = ((unsigned int)u) << 16; return c.f;
}
__device__ __forceinline__ float bflo(unsigned int u) {
  union { unsigned int i; float f; } c; c.i = u << 16; return c.f;
}
__device__ __forceinline__ float bfhi(unsigned int u) {
  union { unsigned int i; float f; } c; c.i = u & 0xFFFF0000u; return c.f;
}
__device__ __forceinline__ unsigned short f2bf(float f) {
  union { float f; unsigned int i; } c; c.f = f;
  unsigned int x = c.i;
  x += 0x7FFFu + ((x >> 16) & 1u);
  return (unsigned short)(x >> 16);
}
__device__ __forceinline__ unsigned int pack2(float a, float b) {
  return (unsigned int)f2bf(a) | ((unsigned int)f2bf(b) << 16);
}
__device__ __forceinline__ float siluf(float x) { return x / (1.f + __expf(-x)); }
__device__ __forceinline__ float redsum32(float v) {
  #pragma unroll
  for (int m = 16; m >= 1; m >>= 1) v += __shfl_xor(v, m);
  return v;
}
__device__ __forceinline__ void async_copy16(void* lds, const void* gsrc) {
  __builtin_amdgcn_global_load_lds((const GAS unsigned int*)gsrc,
                                   (LAS unsigned int*)lds, 16, 0, 0);
}

// ---- DPP helpers ----
template<int CTRL>
__device__ __forceinline__ float dpp_add(float x) {
  union { int i; float f; } a, r;
  a.f = x;
  r.i = __builtin_amdgcn_update_dpp(0, a.i, CTRL, 0xF, 0xF, true);
  return x + r.f;
}
// rotate-based reduction within each 16-lane row: EVERY lane gets the row sum
// (no readlane/broadcast needed).
__device__ __forceinline__ float red16_ror(float x) {
  x = dpp_add<0x121>(x);   // row_ror:1
  x = dpp_add<0x122>(x);   // row_ror:2
  x = dpp_add<0x124>(x);   // row_ror:4
  x = dpp_add<0x128>(x);   // row_ror:8
  return x;
}

// ---------------- cast x (f32 -> bf16) ----------------
__global__ __launch_bounds__(256) void cast_x_kernel(const float* __restrict__ in,
                                                     unsigned short* __restrict__ out) {
  size_t i = ((size_t)blockIdx.x * 256 + threadIdx.x) * 4;
  float4 v = *(const float4*)(in + i);
  uint2 r;
  r.x = pack2(v.x, v.y);
  r.y = pack2(v.z, v.w);
  *(uint2*)(out + i) = r;
}

// ---------------- transpose + cast weight (f32 [R][C] -> bf16 [C][R]) ----------------
__global__ __launch_bounds__(256) void transpose_cast(const float* __restrict__ in,
                                                      unsigned short* __restrict__ out,
                                                      int R, int Cc) {
  __shared__ float tile[32][33];
  int c0 = blockIdx.x * 32, r0 = blockIdx.y * 32;
  int tx = threadIdx.x, ty = threadIdx.y;  // (32,8)
  #pragma unroll
  for (int i = 0; i < 4; ++i)
    tile[ty + i*8][tx] = in[(size_t)(r0 + ty + i*8) * Cc + c0 + tx];
  __syncthreads();
  #pragma unroll
  for (int i = 0; i < 4; ++i)
    out[(size_t)(c0 + ty + i*8) * R + r0 + tx] = f2bf(tile[tx][ty + i*8]);
}

// ---------------- bf16 MFMA GEMM: C[M,N] = A[M,K] * Bt[N,K]^T ----------------
template<int BF16OUT>
__global__ __launch_bounds__(256) void gemm_kernel(
    const unsigned short* __restrict__ A,   // [M][K] bf16
    const unsigned short* __restrict__ Bt,  // [N][K] bf16
    void* __restrict__ Cout,
    int M, int N, int K)
{
  __shared__ __align__(16) unsigned short As[128][32];
  __shared__ __align__(16) unsigned short Bs[128][32];
  const int tid  = threadIdx.x;
  const int lane = tid & 63;
  const int wave = tid >> 6;
  const int wr = wave >> 1, wc = wave & 1;
  const int row0 = blockIdx.y * 128, col0 = blockIdx.x * 128;
  f32x4 acc[4][4];
  #pragma unroll
  for (int m = 0; m < 4; ++m)
    #pragma unroll
    for (int n = 0; n < 4; ++n)
      acc[m][n] = (f32x4){0.f, 0.f, 0.f, 0.f};

  const int fr = lane & 15;   // row within 16x16 frag
  const int fq = lane >> 4;   // k-quad (8 contiguous k per lane)

  for (int k0 = 0; k0 < K; k0 += 32) {
    #pragma unroll
    for (int i = 0; i < 2; ++i) {
      int c = tid + i * 256;          // chunk id 0..511 -> LDS byte c*16 (linear)
      int r = c >> 2, o = (c & 3) * 8;
      async_copy16(&As[r][o], A  + (size_t)(row0 + r) * K + k0 + o);
      async_copy16(&Bs[r][o], Bt + (size_t)(col0 + r) * K + k0 + o);
    }
    asm volatile("s_waitcnt vmcnt(0)" ::: "memory");
    __syncthreads();
    bf16x8 af[4], bfr[4];
    #pragma unroll
    for (int m = 0; m < 4; ++m)
      af[m] = *(const bf16x8*)&As[wr*64 + m*16 + fr][fq*8];
    #pragma unroll
    for (int n = 0; n < 4; ++n)
      bfr[n] = *(const bf16x8*)&Bs[wc*64 + n*16 + fr][fq*8];
    #pragma unroll
    for (int m = 0; m < 4; ++m)
      #pragma unroll
      for (int n = 0; n < 4; ++n)
        acc[m][n] = __builtin_amdgcn_mfma_f32_16x16x32_bf16(af[m], bfr[n], acc[m][n], 0, 0, 0);
    __syncthreads();
  }
  // C/D layout: col = lane&15, row = (lane>>4)*4 + reg
  const int fc = lane & 15, fg = lane >> 4;
  #pragma unroll
  for (int m = 0; m < 4; ++m)
    #pragma unroll
    for (int n = 0; n < 4; ++n)
      #pragma unroll
      for (int r = 0; r < 4; ++r) {
        size_t idx = (size_t)(row0 + wr*64 + m*16 + fg*4 + r) * N
                   + (col0 + wc*64 + n*16 + fc);
        if (BF16OUT) ((unsigned short*)Cout)[idx] = f2bf(acc[m][n][r]);
        else         ((float*)Cout)[idx]          = acc[m][n][r];
      }
}

// ---------------- beta / gamma projection (f32, N=16) ----------------
// Stores interleaved (beta, gamma=exp(g)) pairs so delta does ONE float2 load
// per step and has no transcendental on its critical path.
__global__ __launch_bounds__(256) void beta_g_kernel(
    const float* __restrict__ x, const float* __restrict__ Wb, const float* __restrict__ Wa,
    const float* __restrict__ A_log, const float* __restrict__ dtb,
    float* __restrict__ bg)
{
  const int t = blockIdx.x;
  const int wave = threadIdx.x >> 6;
  const int lane = threadIdx.x & 63;
  const float* xr = x + (size_t)t * D_;
  float acc[4] = {0.f, 0.f, 0.f, 0.f};
  for (int k = lane; k < D_; k += 64) {
    float xv = xr[k];
    #pragma unroll
    for (int i = 0; i < 4; ++i) {
      int o = wave + 4 * i;                 // 0..7: beta heads, 8..15: a heads
      float w = (o < 8) ? Wb[(size_t)k * 8 + o] : Wa[(size_t)k * 8 + (o - 8)];
      acc[i] += xv * w;
    }
  }
  #pragma unroll
  for (int i = 0; i < 4; ++i) {
    #pragma unroll
    for (int m = 32; m >= 1; m >>= 1) acc[i] += __shfl_xor(acc[i], m);
  }
  if (lane == 0) {
    #pragma unroll
    for (int i = 0; i < 4; ++i) {
      int o = wave + 4 * i;
      if (o < 8) {
        bg[((size_t)t * H_ + o) * 2] = 1.f / (1.f + __expf(-acc[i]));
      } else {
        int h = o - 8;
        float z = acc[i] + dtb[h];
        float sp = (z > 20.f) ? z : log1pf(__expf(z));
        bg[((size_t)t * H_ + h) * 2 + 1] = __expf(-__expf(A_log[h]) * sp);
      }
    }
  }
}

// ---------------- causal dwconv(W=4) + silu + l2norm ----------------
__global__ __launch_bounds__(256) void conv_kernel(
    const unsigned short* __restrict__ Y1,
    const float* __restrict__ cq, const float* __restrict__ ck, const float* __restrict__ cv,
    float* __restrict__ qf, float* __restrict__ kf, float* __restrict__ vf)
{
  const int t  = blockIdx.x;          // global row (b*T + tt)
  const int tt = t & (T_ - 1);
  const int tid = threadIdx.x;
  const int c4 = tid * 4;
  const int c8 = tid * 8;

  float wqa[4][4], wka[4][4], wva[8][4];
  #pragma unroll
  for (int m = 0; m < 4; ++m) {
    float4 a = *(const float4*)(cq + (size_t)(c4 + m) * 4);
    wqa[m][0] = a.x; wqa[m][1] = a.y; wqa[m][2] = a.z; wqa[m][3] = a.w;
    float4 b = *(const float4*)(ck + (size_t)(c4 + m) * 4);
    wka[m][0] = b.x; wka[m][1] = b.y; wka[m][2] = b.z; wka[m][3] = b.w;
  }
  #pragma unroll
  for (int m = 0; m < 8; ++m) {
    float4 a = *(const float4*)(cv + (size_t)(c8 + m) * 4);
    wva[m][0] = a.x; wva[m][1] = a.y; wva[m][2] = a.z; wva[m][3] = a.w;
  }

  float aq[4] = {0,0,0,0}, ak[4] = {0,0,0,0}, av[8] = {0,0,0,0,0,0,0,0};
  #pragma unroll
  for (int i = 0; i < 4; ++i) {
    if (tt + i >= 3) {      // tap i reads x[t-3+i]
      const unsigned short* row = Y1 + (size_t)(t + i - 3) * N1_;
      ushort4 yq = *(const ushort4*)(row + c4);
      ushort4 yk = *(const ushort4*)(row + NQK_ + c4);
      int4    yv = *(const int4*)(row + 2 * NQK_ + c8);
      float qv[4] = { bfu(yq.x), bfu(yq.y), bfu(yq.z), bfu(yq.w) };
      float kv[4] = { bfu(yk.x), bfu(yk.y), bfu(yk.z), bfu(yk.w) };
      unsigned int vu[4] = { (unsigned)yv.x, (unsigned)yv.y, (unsigned)yv.z, (unsigned)yv.w };
      float vv[8] = { bflo(vu[0]), bfhi(vu[0]), bflo(vu[1]), bfhi(vu[1]),
                      bflo(vu[2]), bfhi(vu[2]), bflo(vu[3]), bfhi(vu[3]) };
      #pragma unroll
      for (int m = 0; m < 4; ++m) { aq[m] += qv[m] * wqa[m][i]; ak[m] += kv[m] * wka[m][i]; }
      #pragma unroll
      for (int m = 0; m < 8; ++m) av[m] += vv[m] * wva[m][i];
    }
  }
  float sq[4], sk[4], ssq = 0.f, ssk = 0.f;
  #pragma unroll
  for (int m = 0; m < 4; ++m) {
    sq[m] = siluf(aq[m]); ssq += sq[m] * sq[m];
    sk[m] = siluf(ak[m]); ssk += sk[m] * sk[m];
  }
  ssq = redsum32(ssq);   // head = tid/32; 32-lane groups align with heads
  ssk = redsum32(ssk);
  float scq = rsqrtf(ssq + 1e-6f) * 0.08838834764831845f;  // * DK^-0.5
  float sck = rsqrtf(ssk + 1e-6f);
  float4 oq = { sq[0]*scq, sq[1]*scq, sq[2]*scq, sq[3]*scq };
  float4 ok = { sk[0]*sck, sk[1]*sck, sk[2]*sck, sk[3]*sck };
  *(float4*)(qf + (size_t)t * NQK_ + c4) = oq;
  *(float4*)(kf + (size_t)t * NQK_ + c4) = ok;
  float4 ov0 = { siluf(av[0]), siluf(av[1]), siluf(av[2]), siluf(av[3]) };
  float4 ov1 = { siluf(av[4]), siluf(av[5]), siluf(av[6]), siluf(av[7]) };
  *(float4*)(vf + (size_t)t * NV_ + c8)     = ov0;
  *(float4*)(vf + (size_t)t * NV_ + c8 + 4) = ov1;
}

// ---------------- gated delta-rule recurrence ----------------
// 16-lane groups: each group owns one DV-column, 8 state elems/lane (DK=128).
// 4 columns per wave, 1024 blocks (= 1 wave/SIMD; wave count is fixed by the
// 4096 independent (b,h,j) chains / 4 cols per wave).
// launch_bounds(64,1): allocator must NOT shrink live ranges for occupancy —
// round-5 showed it collapsed the 8-slot pipeline to 92 VGPRs, sinking loads
// to their uses and exposing full memory latency (VALUBusy 36%, 64% stall).
// sched_barrier(0) after each PREF pins each slot's loads ~7 steps ahead.
// Over-read audit (rows up to T+7): qf->kf, kf->vf, vf->Wot(+64KB, read-only),
// bg->Y1 — all inside ws, read-only. o aliases vf: reads stay >=8 rows ahead
// of the store row; columns disjoint across waves.
__global__ __launch_bounds__(64, 1) void delta_kernel(
    const float* __restrict__ qf, const float* __restrict__ kf,
    const float* __restrict__ vf, const float* __restrict__ bg,
    float* __restrict__ o)
{
  const int blk = blockIdx.x;
  const int bh = blk & 15;     // fastest-varying -> same bh clusters per XCD
  const int jq = blk >> 4;     // 0..63 column quad
  const int b = bh >> 3, h = bh & 7;
  const int lane = threadIdx.x;
  const int r = lane & 15;
  const int j = jq * 4 + (lane >> 4);

  const int SQK = H_ * DK_;    // 1024
  const int SV  = H_ * DV_;    // 2048

  const float* qp = qf + (size_t)(b * T_) * SQK + h * DK_ + r * 8;
  const float* kp = kf + (size_t)(b * T_) * SQK + h * DK_ + r * 8;
  const float* vp = vf + (size_t)(b * T_) * SV + h * DV_ + j;
  const float* gp = bg + ((size_t)(b * T_) * H_ + h) * 2;
  float*       op = o  + (size_t)(b * T_) * SV + h * DV_ + j;

  float4 Sa = {0,0,0,0}, Sb = {0,0,0,0};

  float4 ka0,kb0,qa0,qb0, ka1,kb1,qa1,qb1, ka2,kb2,qa2,qb2, ka3,kb3,qa3,qb3,
         ka4,kb4,qa4,qb4, ka5,kb5,qa5,qb5, ka6,kb6,qa6,qb6, ka7,kb7,qa7,qb7;
  float  vv0,vv1,vv2,vv3,vv4,vv5,vv6,vv7;
  float2 bgv0,bgv1,bgv2,bgv3,bgv4,bgv5,bgv6,bgv7;

#define PREF(SL, ROW) do { \
    ka##SL = *(const float4*)(kp + (ROW) * SQK); \
    kb##SL = *(const float4*)(kp + (ROW) * SQK + 4); \
    qa##SL = *(const float4*)(qp + (ROW) * SQK); \
    qb##SL = *(const float4*)(qp + (ROW) * SQK + 4); \
    vv##SL = vp[(ROW) * SV]; \
    bgv##SL = *(const float2*)(gp + (ROW) * (H_ * 2)); \
    __builtin_amdgcn_sched_barrier(0); \
  } while (0)

#define STEP(SL) do { \
    float p0 = ka##SL.x*Sa.x, p1 = ka##SL.y*Sa.y, p2 = ka##SL.z*Sa.z, p3 = ka##SL.w*Sa.w; \
    float p4 = kb##SL.x*Sb.x, p5 = kb##SL.y*Sb.y, p6 = kb##SL.z*Sb.z, p7 = kb##SL.w*Sb.w; \
    float part = ((p0 + p1) + (p2 + p3)) + ((p4 + p5) + (p6 + p7)); \
    float dot = red16_ror(part); \
    float gm = bgv##SL.y; \
    float u = bgv##SL.x * fmaf(-gm, dot, vv##SL); \
    Sa.x = fmaf(gm, Sa.x, ka##SL.x * u); \
    Sa.y = fmaf(gm, Sa.y, ka##SL.y * u); \
    Sa.z = fmaf(gm, Sa.z, ka##SL.z * u); \
    Sa.w = fmaf(gm, Sa.w, ka##SL.w * u); \
    Sb.x = fmaf(gm, Sb.x, kb##SL.x * u); \
    Sb.y = fmaf(gm, Sb.y, kb##SL.y * u); \
    Sb.z = fmaf(gm, Sb.z, kb##SL.z * u); \
    Sb.w = fmaf(gm, Sb.w, kb##SL.w * u); \
    float o0 = qa##SL.x*Sa.x, o1 = qa##SL.y*Sa.y, o2 = qa##SL.z*Sa.z, o3 = qa##SL.w*Sa.w; \
    float o4 = qb##SL.x*Sb.x, o5 = qb##SL.y*Sb.y, o6 = qb##SL.z*Sb.z, o7 = qb##SL.w*Sb.w; \
    float pov = ((o0 + o1) + (o2 + o3)) + ((o4 + o5) + (o6 + o7)); \
    float od = red16_ror(pov); \
    if (r == 0) *op = od; \
    op += SV; \
  } while (0)

  // prologue: rows 0..7 into slots 0..7
  PREF(0,0); PREF(1,1); PREF(2,2); PREF(3,3);
  PREF(4,4); PREF(5,5); PREF(6,6); PREF(7,7);
  qp += 8 * SQK; kp += 8 * SQK; vp += 8 * SV; gp += 8 * (H_ * 2);

  for (int t = 0; t < T_; t += 8) {
    STEP(0); PREF(0,0);
    STEP(1); PREF(1,1);
    STEP(2); PREF(2,2);
    STEP(3); PREF(3,3);
    STEP(4); PREF(4,4);
    STEP(5); PREF(5,5);
    STEP(6); PREF(6,6);
    STEP(7); PREF(7,7);
    qp += 8 * SQK; kp += 8 * SQK; vp += 8 * SV; gp += 8 * (H_ * 2);
  }
#undef PREF
#undef STEP
}

// ---------------- gated RMSNorm + silu(gate) -> bf16 ----------------
__global__ __launch_bounds__(256) void post_kernel(
    const float* __restrict__ o, const unsigned short* __restrict__ Y1,
    const float* __restrict__ gw, unsigned short* __restrict__ og)
{
  const int t = blockIdx.x;
  const int tid = threadIdx.x;
  const int e = tid * 8;       // head = tid/32, dv = e&255
  float4 v0 = *(const float4*)(o + (size_t)t * NV_ + e);
  float4 v1 = *(const float4*)(o + (size_t)t * NV_ + e + 4);
  float v[8] = { v0.x, v0.y, v0.z, v0.w, v1.x, v1.y, v1.z, v1.w };
  float ss = 0.f;
  #pragma unroll
  for (int m = 0; m < 8; ++m) ss += v[m] * v[m];
  ss = redsum32(ss);
  float rms = rsqrtf(ss * (1.f / 256.f) + 1e-5f);
  int4 graw = *(const int4*)(Y1 + (size_t)t * N1_ + 4096 + e);
  unsigned int gu[4] = { (unsigned)graw.x, (unsigned)graw.y, (unsigned)graw.z, (unsigned)graw.w };
  float gv[8] = { bflo(gu[0]), bfhi(gu[0]), bflo(gu[1]), bfhi(gu[1]),
                  bflo(gu[2]), bfhi(gu[2]), bflo(gu[3]), bfhi(gu[3]) };
  const int dv = e & 255;
  float res[8];
  #pragma unroll
  for (int m = 0; m < 8; ++m) res[m] = v[m] * rms * gw[dv + m] * siluf(gv[m]);
  int4 outv;
  outv.x = (int)pack2(res[0], res[1]);
  outv.y = (int)pack2(res[2], res[3]);
  outv.z = (int)pack2(res[4], res[5]);
  outv.w = (int)pack2(res[6], res[7]);
  *(int4*)(og + (size_t)t * NV_ + e) = outv;
}

extern "C" void kernel_launch(void* const* d_in, const int* in_sizes, int n_in,
                              void* d_out, int out_size, void* d_ws, size_t ws_size,
                              hipStream_t stream)
{
  (void)in_sizes; (void)n_in; (void)out_size;
  const float* x     = (const float*)d_in[0];
  const float* Wq    = (const float*)d_in[1];
  const float* Wk    = (const float*)d_in[2];
  const float* Wv    = (const float*)d_in[3];
  const float* Wb    = (const float*)d_in[4];
  const float* Wa    = (const float*)d_in[5];
  const float* Wg    = (const float*)d_in[6];
  const float* Wo    = (const float*)d_in[7];
  const float* cq    = (const float*)d_in[8];
  const float* ck    = (const float*)d_in[9];
  const float* cv    = (const float*)d_in[10];
  const float* A_log = (const float*)d_in[11];
  const float* dtb   = (const float*)d_in[12];
  const float* gw    = (const float*)d_in[13];

  // ---- workspace layout with lifetime-based aliasing (peak ~232.5 MiB) ----
  // Region R1 [0, 128MiB):
  //   phase A (cast/transpose/gemm1): xb [0,32MiB) + Wct [32,56MiB)
  //   phase B (conv/delta):           qf [0,32MiB) + kf [32,64MiB) + vf/ov [64,128MiB)
  //   phase C (post/gemm2):           og [0,32MiB)  (qf dead)
  // Then: Wot (8MiB), bg (512KiB), Y1 (96MiB). Ordering guarantees delta's
  // 8-row prefetch over-read of qf/kf/vf/bg lands in the next live buffer.
  char* ws = (char*)d_ws;
  const size_t SZ_XB  = (size_t)BT_ * D_ * 2;       // 32 MiB
  const size_t SZ_WCT = (size_t)N1_ * D_ * 2;       // 24 MiB
  const size_t SZ_QF  = (size_t)BT_ * NQK_ * 4;     // 32 MiB
  const size_t SZ_KF  = (size_t)BT_ * NQK_ * 4;     // 32 MiB
  const size_t SZ_VF  = (size_t)BT_ * NV_ * 4;      // 64 MiB
  const size_t SZ_R1a = SZ_XB + SZ_WCT;
  const size_t SZ_R1b = SZ_QF + SZ_KF + SZ_VF;
  const size_t SZ_R1  = (SZ_R1a > SZ_R1b) ? SZ_R1a : SZ_R1b;
  const size_t SZ_WOT = (size_t)D_ * D_ * 2;        // 8 MiB
  const size_t SZ_BG  = (size_t)BT_ * H_ * 8;       // 512 KiB (float2)
  const size_t SZ_Y1  = (size_t)BT_ * N1_ * 2;      // 96 MiB

  const size_t OFF_WOT = SZ_R1;
  const size_t OFF_BG  = OFF_WOT + SZ_WOT;
  const size_t OFF_Y1  = OFF_BG + SZ_BG;
  const size_t WS_NEEDED = OFF_Y1 + SZ_Y1;
  if (ws_size < WS_NEEDED) return;   // diagnostic: absmax == ref-max ==> ws too small

  unsigned short* xb  = (unsigned short*)(ws);                 // phase A
  unsigned short* Wct = (unsigned short*)(ws + SZ_XB);         // phase A
  float* qf = (float*)(ws);                                    // phase B
  float* kf = (float*)(ws + SZ_QF);                            // phase B
  float* vf = (float*)(ws + SZ_QF + SZ_KF);                    // phase B/C (ov aliases)
  float* ov = vf;
  unsigned short* og  = (unsigned short*)(ws);                 // phase C
  unsigned short* Wot = (unsigned short*)(ws + OFF_WOT);
  float* bg   = (float*)(ws + OFF_BG);
  unsigned short* Y1  = (unsigned short*)(ws + OFF_Y1);

  cast_x_kernel<<<(BT_ * D_) / 1024, 256, 0, stream>>>(x, xb);
  dim3 tb(32, 8);
  transpose_cast<<<dim3(1024/32, 2048/32), tb, 0, stream>>>(Wq, Wct, 2048, 1024);
  transpose_cast<<<dim3(1024/32, 2048/32), tb, 0, stream>>>(Wk, Wct + (size_t)1024 * 2048, 2048, 1024);
  transpose_cast<<<dim3(2048/32, 2048/32), tb, 0, stream>>>(Wv, Wct + (size_t)2048 * 2048, 2048, 2048);
  transpose_cast<<<dim3(2048/32, 2048/32), tb, 0, stream>>>(Wg, Wct + (size_t)4096 * 2048, 2048, 2048);
  transpose_cast<<<dim3(2048/32, 2048/32), tb, 0, stream>>>(Wo, Wot, 2048, 2048);

  gemm_kernel<1><<<dim3(N1_/128, BT_/128), 256, 0, stream>>>(xb, Wct, Y1, BT_, N1_, D_);
  beta_g_kernel<<<BT_, 256, 0, stream>>>(x, Wb, Wa, A_log, dtb, bg);
  conv_kernel<<<BT_, 256, 0, stream>>>(Y1, cq, ck, cv, qf, kf, vf);
  delta_kernel<<<B_ * H_ * (DV_/4), 64, 0, stream>>>(qf, kf, vf, bg, ov);
  post_kernel<<<BT_, 256, 0, stream>>>(ov, Y1, gw, og);
  gemm_kernel<0><<<dim3(D_/128, BT_/128), 256, 0, stream>>>(og, Wot, d_out, BT_, D_, D_);
}